// Round 18
// baseline (296.868 us; speedup 1.0000x reference)
//
#include <hip/hip_runtime.h>

typedef __attribute__((ext_vector_type(8))) short bf16x8_t;
typedef __attribute__((ext_vector_type(4))) float f32x4_t;

#define PINF(x) asm volatile("" : "+v"(x))

// ---------------- partition: edges -> coarse buckets (256 nodes each) ----------------

#define PCHUNK 4096
#define PTHREADS 512
#define EPT (PCHUNK / PTHREADS)
#define NBUCK_MAX 400
#define BCAP 6144

__global__ __launch_bounds__(PTHREADS)
void k_partition2(const int* __restrict__ src, const int* __restrict__ dst,
                  int* __restrict__ bcnt, unsigned int* __restrict__ stageg,
                  int E, int nbuck) {
    __shared__ int hist[NBUCK_MAX];
    __shared__ int boffs[NBUCK_MAX];
    __shared__ int cur[NBUCK_MAX];
    __shared__ int gbase[NBUCK_MAX];
    __shared__ int tmp[PTHREADS];
    __shared__ unsigned int stage[PCHUNK];
    __shared__ unsigned short sbid[PCHUNK];

    int tid = threadIdx.x;
    int ebase = blockIdx.x * PCHUNK;
    int ecount = min(PCHUNK, E - ebase);

    if (tid < NBUCK_MAX) hist[tid] = 0;
    __syncthreads();

    int dreg[EPT], sreg[EPT];
#pragma unroll
    for (int k = 0; k < EPT; k++) {
        int e = ebase + tid + k * PTHREADS;
        if (tid + k * PTHREADS < ecount) {
            dreg[k] = dst[e];
            sreg[k] = src[e];
            atomicAdd(&hist[dreg[k] >> 8], 1);
        } else dreg[k] = -1;
    }
    __syncthreads();

    int v = (tid < nbuck) ? hist[tid] : 0;
    tmp[tid] = v;
    __syncthreads();
    for (int d = 1; d < PTHREADS; d <<= 1) {
        int t = (tid >= d) ? tmp[tid - d] : 0;
        __syncthreads();
        tmp[tid] += t;
        __syncthreads();
    }
    if (tid < nbuck) { boffs[tid] = tmp[tid] - v; cur[tid] = tmp[tid] - v; }
    __syncthreads();

#pragma unroll
    for (int k = 0; k < EPT; k++) {
        if (dreg[k] >= 0) {
            int b = dreg[k] >> 8;
            int p = atomicAdd(&cur[b], 1);
            stage[p] = ((unsigned int)(dreg[k] & 255) << 17) | (unsigned int)sreg[k];
            sbid[p] = (unsigned short)b;
        }
    }
    __syncthreads();

    if (tid < nbuck) {
        int c = cur[tid] - boffs[tid];
        if (c > 0) gbase[tid] = atomicAdd(&bcnt[tid], c);
    }
    __syncthreads();

    for (int i = tid; i < ecount; i += PTHREADS) {
        int b = sbid[i];
        stageg[(size_t)b * BCAP + gbase[b] + (i - boffs[b])] = stage[i];
    }
}

// ---------------- bucket scan ----------------

__global__ __launch_bounds__(512)
void k_bucket_scan(const int* __restrict__ bcnt, int* __restrict__ bbase, int nbuck) {
    __shared__ int tmp[512];
    int tid = threadIdx.x;
    int v = (tid < nbuck) ? bcnt[tid] : 0;
    tmp[tid] = v;
    __syncthreads();
    for (int d = 1; d < 512; d <<= 1) {
        int t = (tid >= d) ? tmp[tid - d] : 0;
        __syncthreads();
        tmp[tid] += t;
        __syncthreads();
    }
    if (tid < nbuck) bbase[tid] = tmp[tid] - v;
    if (tid == nbuck - 1) bbase[nbuck] = tmp[tid];
}

// ---------------- fine fill: bucket-staged -> dense CSR (offs, dinv, col) ----------------

__global__ __launch_bounds__(1024)
void k_finefill2(const unsigned int* __restrict__ stageg, const int* __restrict__ bcnt,
                 const int* __restrict__ bbase, int* __restrict__ offs,
                 float* __restrict__ dinv, int* __restrict__ col, int N, int nbuck) {
    __shared__ int cnt0[256];
    __shared__ int excl[256];
    __shared__ int cur[256];
    __shared__ unsigned int stage[BCAP];
    int b = blockIdx.x;
    int tid = threadIdx.x;
    int nbase = b << 8;
    int nn = min(256, N - nbase);
    int n = bcnt[b];
    int base = bbase[b];
    const unsigned int* sg = stageg + (size_t)b * BCAP;

    if (tid < 256) cnt0[tid] = 0;
    __syncthreads();

    for (int i = tid; i < n; i += 1024)
        atomicAdd(&cnt0[sg[i] >> 17], 1);
    __syncthreads();

    if (tid < 256) excl[tid] = cnt0[tid];
    __syncthreads();
    for (int d = 1; d < 256; d <<= 1) {
        int t = 0;
        if (tid < 256 && tid >= d) t = excl[tid - d];
        __syncthreads();
        if (tid < 256) excl[tid] += t;
        __syncthreads();
    }
    if (tid < 256) {
        int e = excl[tid] - cnt0[tid];
        cur[tid] = e;
        if (tid < nn) {
            offs[nbase + tid] = base + e;
            dinv[nbase + tid] = rsqrtf((float)(cnt0[tid] + 1));  // +1 self-loop
        }
    }
    if (b == nbuck - 1 && tid == 0) offs[N] = bbase[nbuck];
    __syncthreads();

    for (int i = tid; i < n; i += 1024) {
        unsigned int v = sg[i];
        int p = atomicAdd(&cur[v >> 17], 1);
        stage[p] = v & 0x1FFFFu;
    }
    __syncthreads();
    for (int i = tid; i < n; i += 1024)
        col[base + i] = (int)stage[i];
}

// ---------------- bf16 helpers ----------------

__device__ __forceinline__ unsigned int bf16rne(float x) {
    unsigned int u = __float_as_uint(x);
    return (u + 0x7FFFu + ((u >> 16) & 1u)) >> 16;
}
__device__ __forceinline__ float u2flo(unsigned int u) { return __uint_as_float(u << 16); }
__device__ __forceinline__ float u2fhi(unsigned int u) { return __uint_as_float(u & 0xFFFF0000u); }

__device__ __forceinline__ void split2(float a, float b, unsigned int& hi, unsigned int& lo) {
    unsigned int ha = bf16rne(a), hb = bf16rne(b);
    float ra = a - u2flo(ha), rb = b - u2flo(hb);
    hi = ha | (hb << 16);
    lo = bf16rne(ra) | (bf16rne(rb) << 16);
}

union FragU { uint4 u4; bf16x8_t bf; };

// ---------------- W fragment precompute (once); block 0 also zeros bcnt ----------------

__global__ __launch_bounds__(256)
void k_wsplit(const float* __restrict__ Wenc, const float* __restrict__ Wg,
              unsigned int* __restrict__ wfragg, int* __restrict__ bcnt) {
    int m = blockIdx.x;                 // 0=enc, 1..4 = Wg layer m-1
    int tid = threadIdx.x;
    if (m == 0 && tid < 256) { bcnt[tid] = 0; bcnt[tid + 256] = 0; }
    const float* W = (m == 0) ? Wenc : (Wg + (size_t)(m - 1) * 4096);
    unsigned int* wb = wfragg + (size_t)m * 4096;
#pragma unroll
    for (int i = 0; i < 16; i++) {
        int flat = tid * 16 + i;
        int mm = flat & 3;
        int l = (flat >> 2) & 63;
        int fp = flat >> 8;
        int p = fp & 1;
        int f = fp >> 1;
        int ct = f >> 1, kh = f & 1;
        int k = kh * 32 + ((l >> 4) << 3) + 2 * mm;
        int c = ct * 16 + (l & 15);
        float w0 = W[k * 64 + c];
        float w1 = W[(k + 1) * 64 + c];
        unsigned int hi, lo;
        split2(w0, w1, hi, lo);
        wb[flat] = p ? lo : hi;
    }
}

// ---------------- Encoder fused: h = x@Wenc + b ; hwb0 = (dinv*h)@Wg0 ----------------

__global__ __launch_bounds__(256)
void k_enc_fused(const float* __restrict__ x, const uint4* __restrict__ wfE,
                 const float* __restrict__ benc, const uint4* __restrict__ wfG,
                 const float* __restrict__ dinv, float* __restrict__ h,
                 unsigned short* __restrict__ hwb_out, int N) {
    __shared__ float hlds[64 * 68];

    int tid = threadIdx.x;
    int lane = tid & 63;
    int w = tid >> 6;
    int rowbase = blockIdx.x * 64 + w * 16;

    FragU ahi[2], alo[2];
    {
        int row = rowbase + (lane & 15);
        int rc = min(row, N - 1);
#pragma unroll
        for (int kh = 0; kh < 2; kh++) {
            const float4* hp = (const float4*)(x + (size_t)rc * 64 + kh * 32 + ((lane >> 4) << 3));
            float4 p0 = hp[0], p1 = hp[1];
            split2(p0.x, p0.y, ahi[kh].u4.x, alo[kh].u4.x);
            split2(p0.z, p0.w, ahi[kh].u4.y, alo[kh].u4.y);
            split2(p1.x, p1.y, ahi[kh].u4.z, alo[kh].u4.z);
            split2(p1.z, p1.w, ahi[kh].u4.w, alo[kh].u4.w);
        }
    }

    f32x4_t acc[4];
#pragma unroll
    for (int ct = 0; ct < 4; ct++) {
        float b = benc[ct * 16 + (lane & 15)];
        acc[ct] = (f32x4_t){b, b, b, b};
    }
#pragma unroll
    for (int ct = 0; ct < 4; ct++) {
#pragma unroll
        for (int kh = 0; kh < 2; kh++) {
            FragU bhi, blo;
            bhi.u4 = wfE[((ct * 2 + kh) * 2 + 0) * 64 + lane];
            blo.u4 = wfE[((ct * 2 + kh) * 2 + 1) * 64 + lane];
            acc[ct] = __builtin_amdgcn_mfma_f32_16x16x32_bf16(ahi[kh].bf, bhi.bf, acc[ct], 0, 0, 0);
            acc[ct] = __builtin_amdgcn_mfma_f32_16x16x32_bf16(alo[kh].bf, bhi.bf, acc[ct], 0, 0, 0);
            acc[ct] = __builtin_amdgcn_mfma_f32_16x16x32_bf16(ahi[kh].bf, blo.bf, acc[ct], 0, 0, 0);
        }
    }

    float dv[4];
#pragma unroll
    for (int r = 0; r < 4; r++) {
        int row = rowbase + ((lane >> 4) << 2) + r;
        dv[r] = dinv[min(row, N - 1)];
    }
#pragma unroll
    for (int ct = 0; ct < 4; ct++) {
#pragma unroll
        for (int r = 0; r < 4; r++) {
            int row = rowbase + ((lane >> 4) << 2) + r;
            float v = acc[ct][r];
            if (row < N) h[(size_t)row * 64 + ct * 16 + (lane & 15)] = v;
            hlds[(w * 16 + ((lane >> 4) << 2) + r) * 68 + ct * 16 + (lane & 15)] = v * dv[r];
        }
    }
    __syncthreads();

    FragU a2hi[2], a2lo[2];
#pragma unroll
    for (int kh = 0; kh < 2; kh++) {
        const float4* hp = (const float4*)(hlds + (w * 16 + (lane & 15)) * 68 + kh * 32 + ((lane >> 4) << 3));
        float4 p0 = hp[0], p1 = hp[1];
        split2(p0.x, p0.y, a2hi[kh].u4.x, a2lo[kh].u4.x);
        split2(p0.z, p0.w, a2hi[kh].u4.y, a2lo[kh].u4.y);
        split2(p1.x, p1.y, a2hi[kh].u4.z, a2lo[kh].u4.z);
        split2(p1.z, p1.w, a2hi[kh].u4.w, a2lo[kh].u4.w);
    }

#pragma unroll
    for (int ct = 0; ct < 4; ct++) {
        f32x4_t a2 = (f32x4_t){0.f, 0.f, 0.f, 0.f};
#pragma unroll
        for (int kh = 0; kh < 2; kh++) {
            FragU bhi, blo;
            bhi.u4 = wfG[((ct * 2 + kh) * 2 + 0) * 64 + lane];
            blo.u4 = wfG[((ct * 2 + kh) * 2 + 1) * 64 + lane];
            a2 = __builtin_amdgcn_mfma_f32_16x16x32_bf16(a2hi[kh].bf, bhi.bf, a2, 0, 0, 0);
            a2 = __builtin_amdgcn_mfma_f32_16x16x32_bf16(a2lo[kh].bf, bhi.bf, a2, 0, 0, 0);
            a2 = __builtin_amdgcn_mfma_f32_16x16x32_bf16(a2hi[kh].bf, blo.bf, a2, 0, 0, 0);
        }
#pragma unroll
        for (int r = 0; r < 4; r++) {
            float v = a2[r];
            float vo = __shfl_xor(v, 1);
            int row = rowbase + ((lane >> 4) << 2) + r;
            if (!(lane & 1) && row < N) {
                unsigned int pk = bf16rne(v) | (bf16rne(vo) << 16);
                *(unsigned int*)(hwb_out + (size_t)row * 64 + ct * 16 + (lane & 15)) = pk;
            }
        }
    }
}

// ---------------- Fused agg + wave-local next-layer GEMM (layers 0..2) ----------------

__global__ __launch_bounds__(256, 4)
void k_agg_fused(const unsigned short* __restrict__ hwb_in, const int* __restrict__ offs,
                 const int* __restrict__ col, const float* __restrict__ dinv,
                 const float* __restrict__ bg, float* __restrict__ h,
                 const uint4* __restrict__ wnext, unsigned short* __restrict__ hwb_out,
                 int N) {
    __shared__ uint4 wlds[16 * 64];

    int tid = threadIdx.x;
#pragma unroll
    for (int i = 0; i < 4; i++)
        wlds[tid + i * 256] = wnext[tid + i * 256];
    __syncthreads();   // before gather: no coupling of gather chains

    int t = blockIdx.x * 256 + tid;
    int wid = t >> 6;
    int lane = tid & 63;
    int G = lane >> 3;
    int L = lane & 7;
    int node = wid * 8 + G;
    bool valid = node < N;
    int nc = valid ? node : N - 1;

    int start = offs[nc];
    int end = valid ? offs[nc + 1] : start;

    float dn = dinv[nc];
    float* hrow = h + (size_t)nc * 64 + L * 8;
    float4 hr0 = ((const float4*)hrow)[0];
    float4 hr1 = ((const float4*)hrow)[1];
    const float* bgp = bg + L * 8;
    float bs0 = bgp[0] + hr0.x, bs1 = bgp[1] + hr0.y, bs2 = bgp[2] + hr0.z, bs3 = bgp[3] + hr0.w;
    float bs4 = bgp[4] + hr1.x, bs5 = bgp[5] + hr1.y, bs6 = bgp[6] + hr1.z, bs7 = bgp[7] + hr1.w;
    PINF(bs0); PINF(bs1); PINF(bs2); PINF(bs3);
    PINF(bs4); PINF(bs5); PINF(bs6); PINF(bs7); PINF(dn);

    uint4 v = ((const uint4*)(hwb_in + (size_t)nc * 64))[L];
    float a0 = u2flo(v.x), a1 = u2fhi(v.x);
    float a2 = u2flo(v.y), a3 = u2fhi(v.y);
    float a4 = u2flo(v.z), a5 = u2fhi(v.z);
    float a6 = u2flo(v.w), a7 = u2fhi(v.w);

    int last = (end > start) ? (end - 1) : 0;
    int e = start;
    int cc0 = col[min(e + 0, last)];
    int cc1 = col[min(e + 1, last)];
    int cc2 = col[min(e + 2, last)];
    int cc3 = col[min(e + 3, last)];
    for (;;) {
        bool act0 = e < end;
        if (__ballot(act0) == 0ULL) break;
        bool act1 = e + 1 < end, act2 = e + 2 < end, act3 = e + 3 < end;
        uint4 v0 = ((const uint4*)(hwb_in + (size_t)cc0 * 64))[L];
        uint4 v1 = ((const uint4*)(hwb_in + (size_t)cc1 * 64))[L];
        uint4 v2 = ((const uint4*)(hwb_in + (size_t)cc2 * 64))[L];
        uint4 v3 = ((const uint4*)(hwb_in + (size_t)cc3 * 64))[L];
        int en = e + 4;
        cc0 = col[min(en + 0, last)];
        cc1 = col[min(en + 1, last)];
        cc2 = col[min(en + 2, last)];
        cc3 = col[min(en + 3, last)];
        if (!act0) { v0.x = 0u; v0.y = 0u; v0.z = 0u; v0.w = 0u; }
        if (!act1) { v1.x = 0u; v1.y = 0u; v1.z = 0u; v1.w = 0u; }
        if (!act2) { v2.x = 0u; v2.y = 0u; v2.z = 0u; v2.w = 0u; }
        if (!act3) { v3.x = 0u; v3.y = 0u; v3.z = 0u; v3.w = 0u; }
        a0 += (u2flo(v0.x) + u2flo(v1.x)) + (u2flo(v2.x) + u2flo(v3.x));
        a1 += (u2fhi(v0.x) + u2fhi(v1.x)) + (u2fhi(v2.x) + u2fhi(v3.x));
        a2 += (u2flo(v0.y) + u2flo(v1.y)) + (u2flo(v2.y) + u2flo(v3.y));
        a3 += (u2fhi(v0.y) + u2fhi(v1.y)) + (u2fhi(v2.y) + u2fhi(v3.y));
        a4 += (u2flo(v0.z) + u2flo(v1.z)) + (u2flo(v2.z) + u2flo(v3.z));
        a5 += (u2fhi(v0.z) + u2fhi(v1.z)) + (u2fhi(v2.z) + u2fhi(v3.z));
        a6 += (u2flo(v0.w) + u2flo(v1.w)) + (u2flo(v2.w) + u2flo(v3.w));
        a7 += (u2fhi(v0.w) + u2fhi(v1.w)) + (u2fhi(v2.w) + u2fhi(v3.w));
        e = en;
    }

    // epilogue (relu on)
    float4 o0, o1;
    o0.x = fmaxf(fmaf(dn, a0, bs0), 0.f);
    o0.y = fmaxf(fmaf(dn, a1, bs1), 0.f);
    o0.z = fmaxf(fmaf(dn, a2, bs2), 0.f);
    o0.w = fmaxf(fmaf(dn, a3, bs3), 0.f);
    o1.x = fmaxf(fmaf(dn, a4, bs4), 0.f);
    o1.y = fmaxf(fmaf(dn, a5, bs5), 0.f);
    o1.z = fmaxf(fmaf(dn, a6, bs6), 0.f);
    o1.w = fmaxf(fmaf(dn, a7, bs7), 0.f);
    if (valid) {
        ((float4*)hrow)[0] = o0;
        ((float4*)hrow)[1] = o1;
    }

    // ---- wave-local fused GEMM: hwb_out[node] = (dinv*h)@Wnext ----
    float sv0 = o0.x * dn, sv1 = o0.y * dn, sv2 = o0.z * dn, sv3 = o0.w * dn;
    float sv4 = o1.x * dn, sv5 = o1.y * dn, sv6 = o1.z * dn, sv7 = o1.w * dn;

    int r = lane & 15;
    int kb = lane >> 4;
    int srcA = (r & 7) * 8 + kb;       // kh=0 source lane
    int srcB = (r & 7) * 8 + 4 + kb;   // kh=1 source lane

    FragU ahi0, alo0, ahi1, alo1;
    {
        float c0 = __shfl(sv0, srcA), c1 = __shfl(sv1, srcA);
        float c2 = __shfl(sv2, srcA), c3 = __shfl(sv3, srcA);
        float c4 = __shfl(sv4, srcA), c5 = __shfl(sv5, srcA);
        float c6 = __shfl(sv6, srcA), c7 = __shfl(sv7, srcA);
        split2(c0, c1, ahi0.u4.x, alo0.u4.x);
        split2(c2, c3, ahi0.u4.y, alo0.u4.y);
        split2(c4, c5, ahi0.u4.z, alo0.u4.z);
        split2(c6, c7, ahi0.u4.w, alo0.u4.w);
    }
    {
        float c0 = __shfl(sv0, srcB), c1 = __shfl(sv1, srcB);
        float c2 = __shfl(sv2, srcB), c3 = __shfl(sv3, srcB);
        float c4 = __shfl(sv4, srcB), c5 = __shfl(sv5, srcB);
        float c6 = __shfl(sv6, srcB), c7 = __shfl(sv7, srcB);
        split2(c0, c1, ahi1.u4.x, alo1.u4.x);
        split2(c2, c3, ahi1.u4.y, alo1.u4.y);
        split2(c4, c5, ahi1.u4.z, alo1.u4.z);
        split2(c6, c7, ahi1.u4.w, alo1.u4.w);
    }

    f32x4_t acc[4];
#pragma unroll
    for (int ct = 0; ct < 4; ct++) acc[ct] = (f32x4_t){0.f, 0.f, 0.f, 0.f};

#pragma unroll
    for (int ct = 0; ct < 4; ct++) {
        FragU bh0, bl0, bh1, bl1;
        bh0.u4 = wlds[((ct * 2 + 0) * 2 + 0) * 64 + lane];
        bl0.u4 = wlds[((ct * 2 + 0) * 2 + 1) * 64 + lane];
        bh1.u4 = wlds[((ct * 2 + 1) * 2 + 0) * 64 + lane];
        bl1.u4 = wlds[((ct * 2 + 1) * 2 + 1) * 64 + lane];
        acc[ct] = __builtin_amdgcn_mfma_f32_16x16x32_bf16(ahi0.bf, bh0.bf, acc[ct], 0, 0, 0);
        acc[ct] = __builtin_amdgcn_mfma_f32_16x16x32_bf16(alo0.bf, bh0.bf, acc[ct], 0, 0, 0);
        acc[ct] = __builtin_amdgcn_mfma_f32_16x16x32_bf16(ahi0.bf, bl0.bf, acc[ct], 0, 0, 0);
        acc[ct] = __builtin_amdgcn_mfma_f32_16x16x32_bf16(ahi1.bf, bh1.bf, acc[ct], 0, 0, 0);
        acc[ct] = __builtin_amdgcn_mfma_f32_16x16x32_bf16(alo1.bf, bh1.bf, acc[ct], 0, 0, 0);
        acc[ct] = __builtin_amdgcn_mfma_f32_16x16x32_bf16(ahi1.bf, bl1.bf, acc[ct], 0, 0, 0);
    }

    int wbase = wid * 8;
#pragma unroll
    for (int ct = 0; ct < 4; ct++) {
#pragma unroll
        for (int rr = 0; rr < 4; rr++) {
            float vv = acc[ct][rr];
            float vo = __shfl_xor(vv, 1);
            int orow = ((lane >> 4) << 2) + rr;
            int onode = wbase + orow;
            if (!(lane & 1) && orow < 8 && onode < N) {
                unsigned int pk = bf16rne(vv) | (bf16rne(vo) << 16);
                *(unsigned int*)(hwb_out + (size_t)onode * 64 + ct * 16 + (lane & 15)) = pk;
            }
        }
    }
}

// ---------------- Final agg + fused MLP readout (layer 3, no relu, no h write) ----------------
// After the epilogue each 8-lane group holds its node's full 64-ch h in regs
// (lane L: ch L*8..L*8+7). MLP 64->32: per-lane partials over its 8 k's + 3-step
// shfl_xor group reduce; 32->16: 2 cols/lane; 16->1: dot + group reduce.
// Saves the 25.6MB h write + 25.6MB readout re-read + one launch.

__global__ __launch_bounds__(256)
void k_agg_out(const unsigned short* __restrict__ hwb, const int* __restrict__ offs,
               const int* __restrict__ col, const float* __restrict__ dinv,
               const float* __restrict__ bg, const float* __restrict__ h,
               const float* __restrict__ W0, const float* __restrict__ b0,
               const float* __restrict__ W1, const float* __restrict__ b1,
               const float* __restrict__ W2, const float* __restrict__ b2,
               float* __restrict__ out, int N) {
    int t = blockIdx.x * blockDim.x + threadIdx.x;
    int wid = t >> 6;
    int lane = threadIdx.x & 63;
    int G = lane >> 3;
    int L = lane & 7;
    int node = wid * 8 + G;
    bool valid = node < N;
    int nc = valid ? node : N - 1;

    int start = offs[nc];
    int end = valid ? offs[nc + 1] : start;

    float dn = dinv[nc];
    const float* hrow = h + (size_t)nc * 64 + L * 8;
    float4 hr0 = ((const float4*)hrow)[0];
    float4 hr1 = ((const float4*)hrow)[1];
    const float* bgp = bg + L * 8;
    float bs0 = bgp[0] + hr0.x, bs1 = bgp[1] + hr0.y, bs2 = bgp[2] + hr0.z, bs3 = bgp[3] + hr0.w;
    float bs4 = bgp[4] + hr1.x, bs5 = bgp[5] + hr1.y, bs6 = bgp[6] + hr1.z, bs7 = bgp[7] + hr1.w;
    PINF(bs0); PINF(bs1); PINF(bs2); PINF(bs3);
    PINF(bs4); PINF(bs5); PINF(bs6); PINF(bs7); PINF(dn);

    uint4 v = ((const uint4*)(hwb + (size_t)nc * 64))[L];
    float a0 = u2flo(v.x), a1 = u2fhi(v.x);
    float a2 = u2flo(v.y), a3 = u2fhi(v.y);
    float a4 = u2flo(v.z), a5 = u2fhi(v.z);
    float a6 = u2flo(v.w), a7 = u2fhi(v.w);

    int last = (end > start) ? (end - 1) : 0;
    int e = start;
    int cc0 = col[min(e + 0, last)];
    int cc1 = col[min(e + 1, last)];
    int cc2 = col[min(e + 2, last)];
    int cc3 = col[min(e + 3, last)];
    for (;;) {
        bool act0 = e < end;
        if (__ballot(act0) == 0ULL) break;
        bool act1 = e + 1 < end, act2 = e + 2 < end, act3 = e + 3 < end;
        uint4 v0 = ((const uint4*)(hwb + (size_t)cc0 * 64))[L];
        uint4 v1 = ((const uint4*)(hwb + (size_t)cc1 * 64))[L];
        uint4 v2 = ((const uint4*)(hwb + (size_t)cc2 * 64))[L];
        uint4 v3 = ((const uint4*)(hwb + (size_t)cc3 * 64))[L];
        int en = e + 4;
        cc0 = col[min(en + 0, last)];
        cc1 = col[min(en + 1, last)];
        cc2 = col[min(en + 2, last)];
        cc3 = col[min(en + 3, last)];
        if (!act0) { v0.x = 0u; v0.y = 0u; v0.z = 0u; v0.w = 0u; }
        if (!act1) { v1.x = 0u; v1.y = 0u; v1.z = 0u; v1.w = 0u; }
        if (!act2) { v2.x = 0u; v2.y = 0u; v2.z = 0u; v2.w = 0u; }
        if (!act3) { v3.x = 0u; v3.y = 0u; v3.z = 0u; v3.w = 0u; }
        a0 += (u2flo(v0.x) + u2flo(v1.x)) + (u2flo(v2.x) + u2flo(v3.x));
        a1 += (u2fhi(v0.x) + u2fhi(v1.x)) + (u2fhi(v2.x) + u2fhi(v3.x));
        a2 += (u2flo(v0.y) + u2flo(v1.y)) + (u2flo(v2.y) + u2flo(v3.y));
        a3 += (u2fhi(v0.y) + u2fhi(v1.y)) + (u2fhi(v2.y) + u2fhi(v3.y));
        a4 += (u2flo(v0.z) + u2flo(v1.z)) + (u2flo(v2.z) + u2flo(v3.z));
        a5 += (u2fhi(v0.z) + u2fhi(v1.z)) + (u2fhi(v2.z) + u2fhi(v3.z));
        a6 += (u2flo(v0.w) + u2flo(v1.w)) + (u2flo(v2.w) + u2flo(v3.w));
        a7 += (u2fhi(v0.w) + u2fhi(v1.w)) + (u2fhi(v2.w) + u2fhi(v3.w));
        e = en;
    }

    // layer-3 h (no relu), kept in registers only
    float hk0 = fmaf(dn, a0, bs0);
    float hk1 = fmaf(dn, a1, bs1);
    float hk2 = fmaf(dn, a2, bs2);
    float hk3 = fmaf(dn, a3, bs3);
    float hk4 = fmaf(dn, a4, bs4);
    float hk5 = fmaf(dn, a5, bs5);
    float hk6 = fmaf(dn, a6, bs6);
    float hk7 = fmaf(dn, a7, bs7);

    // ---- MLP 64->32: per-lane partials over this lane's 8 channels ----
    float t0[32];
#pragma unroll
    for (int c = 0; c < 32; c++) t0[c] = (L == 0) ? b0[c] : 0.f;
    const float* w0p = W0 + (L * 8) * 32;
#pragma unroll
    for (int k = 0; k < 8; k++) {
        float xk = (k == 0) ? hk0 : (k == 1) ? hk1 : (k == 2) ? hk2 : (k == 3) ? hk3
                 : (k == 4) ? hk4 : (k == 5) ? hk5 : (k == 6) ? hk6 : hk7;
        const float* wr = w0p + k * 32;
#pragma unroll
        for (int c = 0; c < 32; c++) t0[c] = fmaf(xk, wr[c], t0[c]);
    }
#pragma unroll
    for (int m = 1; m <= 4; m <<= 1) {
#pragma unroll
        for (int c = 0; c < 32; c++) t0[c] += __shfl_xor(t0[c], m);
    }
#pragma unroll
    for (int c = 0; c < 32; c++) t0[c] = fmaxf(t0[c], 0.f);

    // ---- 32->16: lane computes cols 2L, 2L+1 ----
    float t1a = b1[L * 2], t1b = b1[L * 2 + 1];
#pragma unroll
    for (int k = 0; k < 32; k++) {
        t1a = fmaf(t0[k], W1[k * 16 + L * 2], t1a);
        t1b = fmaf(t0[k], W1[k * 16 + L * 2 + 1], t1b);
    }
    t1a = fmaxf(t1a, 0.f);
    t1b = fmaxf(t1b, 0.f);

    // ---- 16->1: partial dot + group reduce ----
    float y = t1a * W2[L * 2] + t1b * W2[L * 2 + 1];
#pragma unroll
    for (int m = 1; m <= 4; m <<= 1) y += __shfl_xor(y, m);

    if (valid && L == 0) out[node] = y + b2[0];
}

// ---------------- launch ----------------

extern "C" void kernel_launch(void* const* d_in, const int* in_sizes, int n_in,
                              void* d_out, int out_size, void* d_ws, size_t ws_size,
                              hipStream_t stream) {
    const float* x     = (const float*)d_in[0];
    const int*   eidx  = (const int*)d_in[1];
    const float* W_enc = (const float*)d_in[2];
    const float* b_enc = (const float*)d_in[3];
    const float* Wg    = (const float*)d_in[4];
    const float* bg    = (const float*)d_in[5];
    const float* W0    = (const float*)d_in[6];
    const float* b0    = (const float*)d_in[7];
    const float* W1    = (const float*)d_in[8];
    const float* b1    = (const float*)d_in[9];
    const float* W2    = (const float*)d_in[10];
    const float* b2    = (const float*)d_in[11];

    int N = in_sizes[0] / 64;
    int E = in_sizes[1] / 2;
    const int* esrc = eidx;
    const int* edst = eidx + E;
    int nbuck = (N + 255) >> 8;

    char* w = (char*)d_ws;
    auto alloc = [&](size_t bytes) -> char* {
        char* p = w;
        w += (bytes + 255) & ~(size_t)255;
        return p;
    };
    int*   bcnt  = (int*)alloc(512 * 4);
    int*   bbase = (int*)alloc(512 * 4);
    int*   offs  = (int*)alloc((size_t)(N + 1) * 4);
    int*   col   = (int*)alloc((size_t)E * 4);
    unsigned int* stageg = (unsigned int*)alloc((size_t)nbuck * BCAP * 4);
    float* dinv  = (float*)alloc((size_t)N * 4);
    float* h     = (float*)alloc((size_t)N * 64 * 4);
    unsigned short* hwbA = (unsigned short*)alloc((size_t)N * 64 * 2);
    unsigned short* hwbB = (unsigned short*)alloc((size_t)N * 64 * 2);
    unsigned int* wfragg = (unsigned int*)alloc(5 * 4096 * 4);  // 80KB frag images

    k_wsplit<<<5, 256, 0, stream>>>(W_enc, Wg, wfragg, bcnt);
    k_partition2<<<(E + PCHUNK - 1) / PCHUNK, PTHREADS, 0, stream>>>(esrc, edst, bcnt, stageg, E, nbuck);
    k_bucket_scan<<<1, 512, 0, stream>>>(bcnt, bbase, nbuck);
    k_finefill2<<<nbuck, 1024, 0, stream>>>(stageg, bcnt, bbase, offs, dinv, col, N, nbuck);

    int gbE = (N + 63) / 64;
    int aggthreads = ((N + 7) / 8) * 64;
    int aggblocks = (aggthreads + 255) / 256;

    // encoder + layer-0 GEMM fused: h = x@Wenc+b ; hwbA = (dinv*h)@Wg0
    k_enc_fused<<<gbE, 256, 0, stream>>>(
        x, (const uint4*)wfragg, b_enc, (const uint4*)(wfragg + (size_t)1 * 4096),
        dinv, h, hwbA, N);
    // layers 0..2: agg + wave-local next-layer GEMM (ping-pong)
    k_agg_fused<<<aggblocks, 256, 0, stream>>>(hwbA, offs, col, dinv, bg + 0 * 64, h,
                                               (const uint4*)(wfragg + (size_t)2 * 4096), hwbB, N);
    k_agg_fused<<<aggblocks, 256, 0, stream>>>(hwbB, offs, col, dinv, bg + 1 * 64, h,
                                               (const uint4*)(wfragg + (size_t)3 * 4096), hwbA, N);
    k_agg_fused<<<aggblocks, 256, 0, stream>>>(hwbA, offs, col, dinv, bg + 2 * 64, h,
                                               (const uint4*)(wfragg + (size_t)4 * 4096), hwbB, N);
    // layer 3: agg + fused MLP readout (no relu, no h write)
    k_agg_out<<<aggblocks, 256, 0, stream>>>(hwbB, offs, col, dinv, bg + 3 * 64, h,
                                             W0, b0, W1, b1, W2, b2, (float*)d_out, N);
}

// Round 19
// 231.522 us; speedup vs baseline: 1.2822x; 1.2822x over previous
//
#include <hip/hip_runtime.h>

typedef __attribute__((ext_vector_type(8))) short bf16x8_t;
typedef __attribute__((ext_vector_type(4))) float f32x4_t;

#define PINF(x) asm volatile("" : "+v"(x))

// ---------------- partition: edges -> coarse buckets (256 nodes each) ----------------

#define PCHUNK 4096
#define PTHREADS 512
#define EPT (PCHUNK / PTHREADS)
#define NBUCK_MAX 400
#define BCAP 6144

__global__ __launch_bounds__(PTHREADS)
void k_partition2(const int* __restrict__ src, const int* __restrict__ dst,
                  int* __restrict__ bcnt, unsigned int* __restrict__ stageg,
                  int E, int nbuck) {
    __shared__ int hist[NBUCK_MAX];
    __shared__ int boffs[NBUCK_MAX];
    __shared__ int cur[NBUCK_MAX];
    __shared__ int gbase[NBUCK_MAX];
    __shared__ int tmp[PTHREADS];
    __shared__ unsigned int stage[PCHUNK];
    __shared__ unsigned short sbid[PCHUNK];

    int tid = threadIdx.x;
    int ebase = blockIdx.x * PCHUNK;
    int ecount = min(PCHUNK, E - ebase);

    if (tid < NBUCK_MAX) hist[tid] = 0;
    __syncthreads();

    int dreg[EPT], sreg[EPT];
#pragma unroll
    for (int k = 0; k < EPT; k++) {
        int e = ebase + tid + k * PTHREADS;
        if (tid + k * PTHREADS < ecount) {
            dreg[k] = dst[e];
            sreg[k] = src[e];
            atomicAdd(&hist[dreg[k] >> 8], 1);
        } else dreg[k] = -1;
    }
    __syncthreads();

    int v = (tid < nbuck) ? hist[tid] : 0;
    tmp[tid] = v;
    __syncthreads();
    for (int d = 1; d < PTHREADS; d <<= 1) {
        int t = (tid >= d) ? tmp[tid - d] : 0;
        __syncthreads();
        tmp[tid] += t;
        __syncthreads();
    }
    if (tid < nbuck) { boffs[tid] = tmp[tid] - v; cur[tid] = tmp[tid] - v; }
    __syncthreads();

#pragma unroll
    for (int k = 0; k < EPT; k++) {
        if (dreg[k] >= 0) {
            int b = dreg[k] >> 8;
            int p = atomicAdd(&cur[b], 1);
            stage[p] = ((unsigned int)(dreg[k] & 255) << 17) | (unsigned int)sreg[k];
            sbid[p] = (unsigned short)b;
        }
    }
    __syncthreads();

    if (tid < nbuck) {
        int c = cur[tid] - boffs[tid];
        if (c > 0) gbase[tid] = atomicAdd(&bcnt[tid], c);
    }
    __syncthreads();

    for (int i = tid; i < ecount; i += PTHREADS) {
        int b = sbid[i];
        stageg[(size_t)b * BCAP + gbase[b] + (i - boffs[b])] = stage[i];
    }
}

// ---------------- bucket scan ----------------

__global__ __launch_bounds__(512)
void k_bucket_scan(const int* __restrict__ bcnt, int* __restrict__ bbase, int nbuck) {
    __shared__ int tmp[512];
    int tid = threadIdx.x;
    int v = (tid < nbuck) ? bcnt[tid] : 0;
    tmp[tid] = v;
    __syncthreads();
    for (int d = 1; d < 512; d <<= 1) {
        int t = (tid >= d) ? tmp[tid - d] : 0;
        __syncthreads();
        tmp[tid] += t;
        __syncthreads();
    }
    if (tid < nbuck) bbase[tid] = tmp[tid] - v;
    if (tid == nbuck - 1) bbase[nbuck] = tmp[tid];
}

// ---------------- fine fill: bucket-staged -> dense CSR (offs, dinv, col) ----------------

__global__ __launch_bounds__(1024)
void k_finefill2(const unsigned int* __restrict__ stageg, const int* __restrict__ bcnt,
                 const int* __restrict__ bbase, int* __restrict__ offs,
                 float* __restrict__ dinv, int* __restrict__ col, int N, int nbuck) {
    __shared__ int cnt0[256];
    __shared__ int excl[256];
    __shared__ int cur[256];
    __shared__ unsigned int stage[BCAP];
    int b = blockIdx.x;
    int tid = threadIdx.x;
    int nbase = b << 8;
    int nn = min(256, N - nbase);
    int n = bcnt[b];
    int base = bbase[b];
    const unsigned int* sg = stageg + (size_t)b * BCAP;

    if (tid < 256) cnt0[tid] = 0;
    __syncthreads();

    for (int i = tid; i < n; i += 1024)
        atomicAdd(&cnt0[sg[i] >> 17], 1);
    __syncthreads();

    if (tid < 256) excl[tid] = cnt0[tid];
    __syncthreads();
    for (int d = 1; d < 256; d <<= 1) {
        int t = 0;
        if (tid < 256 && tid >= d) t = excl[tid - d];
        __syncthreads();
        if (tid < 256) excl[tid] += t;
        __syncthreads();
    }
    if (tid < 256) {
        int e = excl[tid] - cnt0[tid];
        cur[tid] = e;
        if (tid < nn) {
            offs[nbase + tid] = base + e;
            dinv[nbase + tid] = rsqrtf((float)(cnt0[tid] + 1));  // +1 self-loop
        }
    }
    if (b == nbuck - 1 && tid == 0) offs[N] = bbase[nbuck];
    __syncthreads();

    for (int i = tid; i < n; i += 1024) {
        unsigned int v = sg[i];
        int p = atomicAdd(&cur[v >> 17], 1);
        stage[p] = v & 0x1FFFFu;
    }
    __syncthreads();
    for (int i = tid; i < n; i += 1024)
        col[base + i] = (int)stage[i];
}

// ---------------- bf16 helpers ----------------

__device__ __forceinline__ unsigned int bf16rne(float x) {
    unsigned int u = __float_as_uint(x);
    return (u + 0x7FFFu + ((u >> 16) & 1u)) >> 16;
}
__device__ __forceinline__ float u2flo(unsigned int u) { return __uint_as_float(u << 16); }
__device__ __forceinline__ float u2fhi(unsigned int u) { return __uint_as_float(u & 0xFFFF0000u); }

__device__ __forceinline__ void split2(float a, float b, unsigned int& hi, unsigned int& lo) {
    unsigned int ha = bf16rne(a), hb = bf16rne(b);
    float ra = a - u2flo(ha), rb = b - u2flo(hb);
    hi = ha | (hb << 16);
    lo = bf16rne(ra) | (bf16rne(rb) << 16);
}

union FragU { uint4 u4; bf16x8_t bf; };

// ---------------- W fragment precompute (once); block 0 also zeros bcnt ----------------

__global__ __launch_bounds__(256)
void k_wsplit(const float* __restrict__ Wenc, const float* __restrict__ Wg,
              unsigned int* __restrict__ wfragg, int* __restrict__ bcnt) {
    int m = blockIdx.x;                 // 0=enc, 1..4 = Wg layer m-1
    int tid = threadIdx.x;
    if (m == 0 && tid < 256) { bcnt[tid] = 0; bcnt[tid + 256] = 0; }
    const float* W = (m == 0) ? Wenc : (Wg + (size_t)(m - 1) * 4096);
    unsigned int* wb = wfragg + (size_t)m * 4096;
#pragma unroll
    for (int i = 0; i < 16; i++) {
        int flat = tid * 16 + i;
        int mm = flat & 3;
        int l = (flat >> 2) & 63;
        int fp = flat >> 8;
        int p = fp & 1;
        int f = fp >> 1;
        int ct = f >> 1, kh = f & 1;
        int k = kh * 32 + ((l >> 4) << 3) + 2 * mm;
        int c = ct * 16 + (l & 15);
        float w0 = W[k * 64 + c];
        float w1 = W[(k + 1) * 64 + c];
        unsigned int hi, lo;
        split2(w0, w1, hi, lo);
        wb[flat] = p ? lo : hi;
    }
}

// ---------------- Encoder fused: h = x@Wenc + b ; hwb0 = (dinv*h)@Wg0 ----------------

__global__ __launch_bounds__(256)
void k_enc_fused(const float* __restrict__ x, const uint4* __restrict__ wfE,
                 const float* __restrict__ benc, const uint4* __restrict__ wfG,
                 const float* __restrict__ dinv, float* __restrict__ h,
                 unsigned short* __restrict__ hwb_out, int N) {
    __shared__ float hlds[64 * 68];

    int tid = threadIdx.x;
    int lane = tid & 63;
    int w = tid >> 6;
    int rowbase = blockIdx.x * 64 + w * 16;

    FragU ahi[2], alo[2];
    {
        int row = rowbase + (lane & 15);
        int rc = min(row, N - 1);
#pragma unroll
        for (int kh = 0; kh < 2; kh++) {
            const float4* hp = (const float4*)(x + (size_t)rc * 64 + kh * 32 + ((lane >> 4) << 3));
            float4 p0 = hp[0], p1 = hp[1];
            split2(p0.x, p0.y, ahi[kh].u4.x, alo[kh].u4.x);
            split2(p0.z, p0.w, ahi[kh].u4.y, alo[kh].u4.y);
            split2(p1.x, p1.y, ahi[kh].u4.z, alo[kh].u4.z);
            split2(p1.z, p1.w, ahi[kh].u4.w, alo[kh].u4.w);
        }
    }

    f32x4_t acc[4];
#pragma unroll
    for (int ct = 0; ct < 4; ct++) {
        float b = benc[ct * 16 + (lane & 15)];
        acc[ct] = (f32x4_t){b, b, b, b};
    }
#pragma unroll
    for (int ct = 0; ct < 4; ct++) {
#pragma unroll
        for (int kh = 0; kh < 2; kh++) {
            FragU bhi, blo;
            bhi.u4 = wfE[((ct * 2 + kh) * 2 + 0) * 64 + lane];
            blo.u4 = wfE[((ct * 2 + kh) * 2 + 1) * 64 + lane];
            acc[ct] = __builtin_amdgcn_mfma_f32_16x16x32_bf16(ahi[kh].bf, bhi.bf, acc[ct], 0, 0, 0);
            acc[ct] = __builtin_amdgcn_mfma_f32_16x16x32_bf16(alo[kh].bf, bhi.bf, acc[ct], 0, 0, 0);
            acc[ct] = __builtin_amdgcn_mfma_f32_16x16x32_bf16(ahi[kh].bf, blo.bf, acc[ct], 0, 0, 0);
        }
    }

    float dv[4];
#pragma unroll
    for (int r = 0; r < 4; r++) {
        int row = rowbase + ((lane >> 4) << 2) + r;
        dv[r] = dinv[min(row, N - 1)];
    }
#pragma unroll
    for (int ct = 0; ct < 4; ct++) {
#pragma unroll
        for (int r = 0; r < 4; r++) {
            int row = rowbase + ((lane >> 4) << 2) + r;
            float v = acc[ct][r];
            if (row < N) h[(size_t)row * 64 + ct * 16 + (lane & 15)] = v;
            hlds[(w * 16 + ((lane >> 4) << 2) + r) * 68 + ct * 16 + (lane & 15)] = v * dv[r];
        }
    }
    __syncthreads();

    FragU a2hi[2], a2lo[2];
#pragma unroll
    for (int kh = 0; kh < 2; kh++) {
        const float4* hp = (const float4*)(hlds + (w * 16 + (lane & 15)) * 68 + kh * 32 + ((lane >> 4) << 3));
        float4 p0 = hp[0], p1 = hp[1];
        split2(p0.x, p0.y, a2hi[kh].u4.x, a2lo[kh].u4.x);
        split2(p0.z, p0.w, a2hi[kh].u4.y, a2lo[kh].u4.y);
        split2(p1.x, p1.y, a2hi[kh].u4.z, a2lo[kh].u4.z);
        split2(p1.z, p1.w, a2hi[kh].u4.w, a2lo[kh].u4.w);
    }

#pragma unroll
    for (int ct = 0; ct < 4; ct++) {
        f32x4_t a2 = (f32x4_t){0.f, 0.f, 0.f, 0.f};
#pragma unroll
        for (int kh = 0; kh < 2; kh++) {
            FragU bhi, blo;
            bhi.u4 = wfG[((ct * 2 + kh) * 2 + 0) * 64 + lane];
            blo.u4 = wfG[((ct * 2 + kh) * 2 + 1) * 64 + lane];
            a2 = __builtin_amdgcn_mfma_f32_16x16x32_bf16(a2hi[kh].bf, bhi.bf, a2, 0, 0, 0);
            a2 = __builtin_amdgcn_mfma_f32_16x16x32_bf16(a2lo[kh].bf, bhi.bf, a2, 0, 0, 0);
            a2 = __builtin_amdgcn_mfma_f32_16x16x32_bf16(a2hi[kh].bf, blo.bf, a2, 0, 0, 0);
        }
#pragma unroll
        for (int r = 0; r < 4; r++) {
            float v = a2[r];
            float vo = __shfl_xor(v, 1);
            int row = rowbase + ((lane >> 4) << 2) + r;
            if (!(lane & 1) && row < N) {
                unsigned int pk = bf16rne(v) | (bf16rne(vo) << 16);
                *(unsigned int*)(hwb_out + (size_t)row * 64 + ct * 16 + (lane & 15)) = pk;
            }
        }
    }
}

// ---------------- Fused agg + wave-local next-layer GEMM (layers 0..2) ----------------

__global__ __launch_bounds__(256, 4)
void k_agg_fused(const unsigned short* __restrict__ hwb_in, const int* __restrict__ offs,
                 const int* __restrict__ col, const float* __restrict__ dinv,
                 const float* __restrict__ bg, float* __restrict__ h,
                 const uint4* __restrict__ wnext, unsigned short* __restrict__ hwb_out,
                 int N) {
    __shared__ uint4 wlds[16 * 64];

    int tid = threadIdx.x;
#pragma unroll
    for (int i = 0; i < 4; i++)
        wlds[tid + i * 256] = wnext[tid + i * 256];
    __syncthreads();   // before gather: no coupling of gather chains

    int t = blockIdx.x * 256 + tid;
    int wid = t >> 6;
    int lane = tid & 63;
    int G = lane >> 3;
    int L = lane & 7;
    int node = wid * 8 + G;
    bool valid = node < N;
    int nc = valid ? node : N - 1;

    int start = offs[nc];
    int end = valid ? offs[nc + 1] : start;

    float dn = dinv[nc];
    float* hrow = h + (size_t)nc * 64 + L * 8;
    float4 hr0 = ((const float4*)hrow)[0];
    float4 hr1 = ((const float4*)hrow)[1];
    const float* bgp = bg + L * 8;
    float bs0 = bgp[0] + hr0.x, bs1 = bgp[1] + hr0.y, bs2 = bgp[2] + hr0.z, bs3 = bgp[3] + hr0.w;
    float bs4 = bgp[4] + hr1.x, bs5 = bgp[5] + hr1.y, bs6 = bgp[6] + hr1.z, bs7 = bgp[7] + hr1.w;
    PINF(bs0); PINF(bs1); PINF(bs2); PINF(bs3);
    PINF(bs4); PINF(bs5); PINF(bs6); PINF(bs7); PINF(dn);

    uint4 v = ((const uint4*)(hwb_in + (size_t)nc * 64))[L];
    float a0 = u2flo(v.x), a1 = u2fhi(v.x);
    float a2 = u2flo(v.y), a3 = u2fhi(v.y);
    float a4 = u2flo(v.z), a5 = u2fhi(v.z);
    float a6 = u2flo(v.w), a7 = u2fhi(v.w);

    int last = (end > start) ? (end - 1) : 0;
    int e = start;
    int cc0 = col[min(e + 0, last)];
    int cc1 = col[min(e + 1, last)];
    int cc2 = col[min(e + 2, last)];
    int cc3 = col[min(e + 3, last)];
    for (;;) {
        bool act0 = e < end;
        if (__ballot(act0) == 0ULL) break;
        bool act1 = e + 1 < end, act2 = e + 2 < end, act3 = e + 3 < end;
        uint4 v0 = ((const uint4*)(hwb_in + (size_t)cc0 * 64))[L];
        uint4 v1 = ((const uint4*)(hwb_in + (size_t)cc1 * 64))[L];
        uint4 v2 = ((const uint4*)(hwb_in + (size_t)cc2 * 64))[L];
        uint4 v3 = ((const uint4*)(hwb_in + (size_t)cc3 * 64))[L];
        int en = e + 4;
        cc0 = col[min(en + 0, last)];
        cc1 = col[min(en + 1, last)];
        cc2 = col[min(en + 2, last)];
        cc3 = col[min(en + 3, last)];
        if (!act0) { v0.x = 0u; v0.y = 0u; v0.z = 0u; v0.w = 0u; }
        if (!act1) { v1.x = 0u; v1.y = 0u; v1.z = 0u; v1.w = 0u; }
        if (!act2) { v2.x = 0u; v2.y = 0u; v2.z = 0u; v2.w = 0u; }
        if (!act3) { v3.x = 0u; v3.y = 0u; v3.z = 0u; v3.w = 0u; }
        a0 += (u2flo(v0.x) + u2flo(v1.x)) + (u2flo(v2.x) + u2flo(v3.x));
        a1 += (u2fhi(v0.x) + u2fhi(v1.x)) + (u2fhi(v2.x) + u2fhi(v3.x));
        a2 += (u2flo(v0.y) + u2flo(v1.y)) + (u2flo(v2.y) + u2flo(v3.y));
        a3 += (u2fhi(v0.y) + u2fhi(v1.y)) + (u2fhi(v2.y) + u2fhi(v3.y));
        a4 += (u2flo(v0.z) + u2flo(v1.z)) + (u2flo(v2.z) + u2flo(v3.z));
        a5 += (u2fhi(v0.z) + u2fhi(v1.z)) + (u2fhi(v2.z) + u2fhi(v3.z));
        a6 += (u2flo(v0.w) + u2flo(v1.w)) + (u2flo(v2.w) + u2flo(v3.w));
        a7 += (u2fhi(v0.w) + u2fhi(v1.w)) + (u2fhi(v2.w) + u2fhi(v3.w));
        e = en;
    }

    // epilogue (relu on)
    float4 o0, o1;
    o0.x = fmaxf(fmaf(dn, a0, bs0), 0.f);
    o0.y = fmaxf(fmaf(dn, a1, bs1), 0.f);
    o0.z = fmaxf(fmaf(dn, a2, bs2), 0.f);
    o0.w = fmaxf(fmaf(dn, a3, bs3), 0.f);
    o1.x = fmaxf(fmaf(dn, a4, bs4), 0.f);
    o1.y = fmaxf(fmaf(dn, a5, bs5), 0.f);
    o1.z = fmaxf(fmaf(dn, a6, bs6), 0.f);
    o1.w = fmaxf(fmaf(dn, a7, bs7), 0.f);
    if (valid) {
        ((float4*)hrow)[0] = o0;
        ((float4*)hrow)[1] = o1;
    }

    // ---- wave-local fused GEMM: hwb_out[node] = (dinv*h)@Wnext ----
    float sv0 = o0.x * dn, sv1 = o0.y * dn, sv2 = o0.z * dn, sv3 = o0.w * dn;
    float sv4 = o1.x * dn, sv5 = o1.y * dn, sv6 = o1.z * dn, sv7 = o1.w * dn;

    int r = lane & 15;
    int kb = lane >> 4;
    int srcA = (r & 7) * 8 + kb;       // kh=0 source lane
    int srcB = (r & 7) * 8 + 4 + kb;   // kh=1 source lane

    FragU ahi0, alo0, ahi1, alo1;
    {
        float c0 = __shfl(sv0, srcA), c1 = __shfl(sv1, srcA);
        float c2 = __shfl(sv2, srcA), c3 = __shfl(sv3, srcA);
        float c4 = __shfl(sv4, srcA), c5 = __shfl(sv5, srcA);
        float c6 = __shfl(sv6, srcA), c7 = __shfl(sv7, srcA);
        split2(c0, c1, ahi0.u4.x, alo0.u4.x);
        split2(c2, c3, ahi0.u4.y, alo0.u4.y);
        split2(c4, c5, ahi0.u4.z, alo0.u4.z);
        split2(c6, c7, ahi0.u4.w, alo0.u4.w);
    }
    {
        float c0 = __shfl(sv0, srcB), c1 = __shfl(sv1, srcB);
        float c2 = __shfl(sv2, srcB), c3 = __shfl(sv3, srcB);
        float c4 = __shfl(sv4, srcB), c5 = __shfl(sv5, srcB);
        float c6 = __shfl(sv6, srcB), c7 = __shfl(sv7, srcB);
        split2(c0, c1, ahi1.u4.x, alo1.u4.x);
        split2(c2, c3, ahi1.u4.y, alo1.u4.y);
        split2(c4, c5, ahi1.u4.z, alo1.u4.z);
        split2(c6, c7, ahi1.u4.w, alo1.u4.w);
    }

    f32x4_t acc[4];
#pragma unroll
    for (int ct = 0; ct < 4; ct++) acc[ct] = (f32x4_t){0.f, 0.f, 0.f, 0.f};

#pragma unroll
    for (int ct = 0; ct < 4; ct++) {
        FragU bh0, bl0, bh1, bl1;
        bh0.u4 = wlds[((ct * 2 + 0) * 2 + 0) * 64 + lane];
        bl0.u4 = wlds[((ct * 2 + 0) * 2 + 1) * 64 + lane];
        bh1.u4 = wlds[((ct * 2 + 1) * 2 + 0) * 64 + lane];
        bl1.u4 = wlds[((ct * 2 + 1) * 2 + 1) * 64 + lane];
        acc[ct] = __builtin_amdgcn_mfma_f32_16x16x32_bf16(ahi0.bf, bh0.bf, acc[ct], 0, 0, 0);
        acc[ct] = __builtin_amdgcn_mfma_f32_16x16x32_bf16(alo0.bf, bh0.bf, acc[ct], 0, 0, 0);
        acc[ct] = __builtin_amdgcn_mfma_f32_16x16x32_bf16(ahi0.bf, bl0.bf, acc[ct], 0, 0, 0);
        acc[ct] = __builtin_amdgcn_mfma_f32_16x16x32_bf16(ahi1.bf, bh1.bf, acc[ct], 0, 0, 0);
        acc[ct] = __builtin_amdgcn_mfma_f32_16x16x32_bf16(alo1.bf, bh1.bf, acc[ct], 0, 0, 0);
        acc[ct] = __builtin_amdgcn_mfma_f32_16x16x32_bf16(ahi1.bf, bl1.bf, acc[ct], 0, 0, 0);
    }

    int wbase = wid * 8;
#pragma unroll
    for (int ct = 0; ct < 4; ct++) {
#pragma unroll
        for (int rr = 0; rr < 4; rr++) {
            float vv = acc[ct][rr];
            float vo = __shfl_xor(vv, 1);
            int orow = ((lane >> 4) << 2) + rr;
            int onode = wbase + orow;
            if (!(lane & 1) && orow < 8 && onode < N) {
                unsigned int pk = bf16rne(vv) | (bf16rne(vo) << 16);
                *(unsigned int*)(hwb_out + (size_t)onode * 64 + ct * 16 + (lane & 15)) = pk;
            }
        }
    }
}

// ---------------- Final agg + fused MLP readout v2 (layer 3, spill-proof) ----------------
// Round-18 failure: per-lane t0[32] live across group-reduce -> scratch (VGPR=36,
// 3x slowdown). v2: lane L OWNS output columns; inputs arrive via shfl BROADCASTS
// of the group's hk registers. Max live array = 4 named scalars -> register-resident.
// Stage1 64->32: 4 cols/lane, 64 shfl + 256 FMA. Stage2 32->16: 2 cols/lane,
// 32 shfl + 64 FMA. Stage3: dot + 3-step shfl_xor reduce. No h write, no readout pass.

__global__ __launch_bounds__(256)
void k_agg_out(const unsigned short* __restrict__ hwb, const int* __restrict__ offs,
               const int* __restrict__ col, const float* __restrict__ dinv,
               const float* __restrict__ bg, const float* __restrict__ h,
               const float* __restrict__ W0, const float* __restrict__ b0,
               const float* __restrict__ W1, const float* __restrict__ b1,
               const float* __restrict__ W2, const float* __restrict__ b2,
               float* __restrict__ out, int N) {
    int t = blockIdx.x * blockDim.x + threadIdx.x;
    int wid = t >> 6;
    int lane = threadIdx.x & 63;
    int G = lane >> 3;
    int L = lane & 7;
    int gb = lane & 56;                 // group base lane
    int node = wid * 8 + G;
    bool valid = node < N;
    int nc = valid ? node : N - 1;

    int start = offs[nc];
    int end = valid ? offs[nc + 1] : start;

    float dn = dinv[nc];
    const float* hrow = h + (size_t)nc * 64 + L * 8;
    float4 hr0 = ((const float4*)hrow)[0];
    float4 hr1 = ((const float4*)hrow)[1];
    const float* bgp = bg + L * 8;
    float bs0 = bgp[0] + hr0.x, bs1 = bgp[1] + hr0.y, bs2 = bgp[2] + hr0.z, bs3 = bgp[3] + hr0.w;
    float bs4 = bgp[4] + hr1.x, bs5 = bgp[5] + hr1.y, bs6 = bgp[6] + hr1.z, bs7 = bgp[7] + hr1.w;
    PINF(bs0); PINF(bs1); PINF(bs2); PINF(bs3);
    PINF(bs4); PINF(bs5); PINF(bs6); PINF(bs7); PINF(dn);

    uint4 v = ((const uint4*)(hwb + (size_t)nc * 64))[L];
    float a0 = u2flo(v.x), a1 = u2fhi(v.x);
    float a2 = u2flo(v.y), a3 = u2fhi(v.y);
    float a4 = u2flo(v.z), a5 = u2fhi(v.z);
    float a6 = u2flo(v.w), a7 = u2fhi(v.w);

    int last = (end > start) ? (end - 1) : 0;
    int e = start;
    int cc0 = col[min(e + 0, last)];
    int cc1 = col[min(e + 1, last)];
    int cc2 = col[min(e + 2, last)];
    int cc3 = col[min(e + 3, last)];
    for (;;) {
        bool act0 = e < end;
        if (__ballot(act0) == 0ULL) break;
        bool act1 = e + 1 < end, act2 = e + 2 < end, act3 = e + 3 < end;
        uint4 v0 = ((const uint4*)(hwb + (size_t)cc0 * 64))[L];
        uint4 v1 = ((const uint4*)(hwb + (size_t)cc1 * 64))[L];
        uint4 v2 = ((const uint4*)(hwb + (size_t)cc2 * 64))[L];
        uint4 v3 = ((const uint4*)(hwb + (size_t)cc3 * 64))[L];
        int en = e + 4;
        cc0 = col[min(en + 0, last)];
        cc1 = col[min(en + 1, last)];
        cc2 = col[min(en + 2, last)];
        cc3 = col[min(en + 3, last)];
        if (!act0) { v0.x = 0u; v0.y = 0u; v0.z = 0u; v0.w = 0u; }
        if (!act1) { v1.x = 0u; v1.y = 0u; v1.z = 0u; v1.w = 0u; }
        if (!act2) { v2.x = 0u; v2.y = 0u; v2.z = 0u; v2.w = 0u; }
        if (!act3) { v3.x = 0u; v3.y = 0u; v3.z = 0u; v3.w = 0u; }
        a0 += (u2flo(v0.x) + u2flo(v1.x)) + (u2flo(v2.x) + u2flo(v3.x));
        a1 += (u2fhi(v0.x) + u2fhi(v1.x)) + (u2fhi(v2.x) + u2fhi(v3.x));
        a2 += (u2flo(v0.y) + u2flo(v1.y)) + (u2flo(v2.y) + u2flo(v3.y));
        a3 += (u2fhi(v0.y) + u2fhi(v1.y)) + (u2fhi(v2.y) + u2fhi(v3.y));
        a4 += (u2flo(v0.z) + u2flo(v1.z)) + (u2flo(v2.z) + u2flo(v3.z));
        a5 += (u2fhi(v0.z) + u2fhi(v1.z)) + (u2fhi(v2.z) + u2fhi(v3.z));
        a6 += (u2flo(v0.w) + u2flo(v1.w)) + (u2flo(v2.w) + u2flo(v3.w));
        a7 += (u2fhi(v0.w) + u2fhi(v1.w)) + (u2fhi(v2.w) + u2fhi(v3.w));
        e = en;
    }

    // layer-3 h (no relu), registers only: lane L holds channels L*8..L*8+7
    float hk0 = fmaf(dn, a0, bs0);
    float hk1 = fmaf(dn, a1, bs1);
    float hk2 = fmaf(dn, a2, bs2);
    float hk3 = fmaf(dn, a3, bs3);
    float hk4 = fmaf(dn, a4, bs4);
    float hk5 = fmaf(dn, a5, bs5);
    float hk6 = fmaf(dn, a6, bs6);
    float hk7 = fmaf(dn, a7, bs7);

    // ---- stage 1 (64->32): lane owns cols L*4..L*4+3 ----
    int c0 = L * 4;
    float t0a = b0[c0 + 0], t0b = b0[c0 + 1], t0c = b0[c0 + 2], t0d = b0[c0 + 3];
#pragma unroll
    for (int s = 0; s < 8; s++) {
        float y0 = __shfl(hk0, gb + s), y1 = __shfl(hk1, gb + s);
        float y2 = __shfl(hk2, gb + s), y3 = __shfl(hk3, gb + s);
        float y4 = __shfl(hk4, gb + s), y5 = __shfl(hk5, gb + s);
        float y6 = __shfl(hk6, gb + s), y7 = __shfl(hk7, gb + s);
        const float* wp = W0 + (s * 8) * 32 + c0;
#pragma unroll
        for (int j = 0; j < 8; j++) {
            float yj = (j == 0) ? y0 : (j == 1) ? y1 : (j == 2) ? y2 : (j == 3) ? y3
                     : (j == 4) ? y4 : (j == 5) ? y5 : (j == 6) ? y6 : y7;
            const float* wr = wp + j * 32;
            t0a = fmaf(yj, wr[0], t0a);
            t0b = fmaf(yj, wr[1], t0b);
            t0c = fmaf(yj, wr[2], t0c);
            t0d = fmaf(yj, wr[3], t0d);
        }
    }
    t0a = fmaxf(t0a, 0.f); t0b = fmaxf(t0b, 0.f);
    t0c = fmaxf(t0c, 0.f); t0d = fmaxf(t0d, 0.f);

    // ---- stage 2 (32->16): lane owns cols L*2, L*2+1 ----
    float t1a = b1[L * 2], t1b = b1[L * 2 + 1];
#pragma unroll
    for (int s = 0; s < 8; s++) {
        float z0 = __shfl(t0a, gb + s), z1 = __shfl(t0b, gb + s);
        float z2 = __shfl(t0c, gb + s), z3 = __shfl(t0d, gb + s);
        const float* wp = W1 + (s * 4) * 16 + L * 2;
        t1a = fmaf(z0, wp[0], t1a);       t1b = fmaf(z0, wp[1], t1b);
        t1a = fmaf(z1, wp[16], t1a);      t1b = fmaf(z1, wp[17], t1b);
        t1a = fmaf(z2, wp[32], t1a);      t1b = fmaf(z2, wp[33], t1b);
        t1a = fmaf(z3, wp[48], t1a);      t1b = fmaf(z3, wp[49], t1b);
    }
    t1a = fmaxf(t1a, 0.f);
    t1b = fmaxf(t1b, 0.f);

    // ---- stage 3 (16->1) ----
    float y = t1a * W2[L * 2] + t1b * W2[L * 2 + 1];
    y += __shfl_xor(y, 1);
    y += __shfl_xor(y, 2);
    y += __shfl_xor(y, 4);

    if (valid && L == 0) out[node] = y + b2[0];
}

// ---------------- launch ----------------

extern "C" void kernel_launch(void* const* d_in, const int* in_sizes, int n_in,
                              void* d_out, int out_size, void* d_ws, size_t ws_size,
                              hipStream_t stream) {
    const float* x     = (const float*)d_in[0];
    const int*   eidx  = (const int*)d_in[1];
    const float* W_enc = (const float*)d_in[2];
    const float* b_enc = (const float*)d_in[3];
    const float* Wg    = (const float*)d_in[4];
    const float* bg    = (const float*)d_in[5];
    const float* W0    = (const float*)d_in[6];
    const float* b0    = (const float*)d_in[7];
    const float* W1    = (const float*)d_in[8];
    const float* b1    = (const float*)d_in[9];
    const float* W2    = (const float*)d_in[10];
    const float* b2    = (const float*)d_in[11];

    int N = in_sizes[0] / 64;
    int E = in_sizes[1] / 2;
    const int* esrc = eidx;
    const int* edst = eidx + E;
    int nbuck = (N + 255) >> 8;

    char* w = (char*)d_ws;
    auto alloc = [&](size_t bytes) -> char* {
        char* p = w;
        w += (bytes + 255) & ~(size_t)255;
        return p;
    };
    int*   bcnt  = (int*)alloc(512 * 4);
    int*   bbase = (int*)alloc(512 * 4);
    int*   offs  = (int*)alloc((size_t)(N + 1) * 4);
    int*   col   = (int*)alloc((size_t)E * 4);
    unsigned int* stageg = (unsigned int*)alloc((size_t)nbuck * BCAP * 4);
    float* dinv  = (float*)alloc((size_t)N * 4);
    float* h     = (float*)alloc((size_t)N * 64 * 4);
    unsigned short* hwbA = (unsigned short*)alloc((size_t)N * 64 * 2);
    unsigned short* hwbB = (unsigned short*)alloc((size_t)N * 64 * 2);
    unsigned int* wfragg = (unsigned int*)alloc(5 * 4096 * 4);  // 80KB frag images

    k_wsplit<<<5, 256, 0, stream>>>(W_enc, Wg, wfragg, bcnt);
    k_partition2<<<(E + PCHUNK - 1) / PCHUNK, PTHREADS, 0, stream>>>(esrc, edst, bcnt, stageg, E, nbuck);
    k_bucket_scan<<<1, 512, 0, stream>>>(bcnt, bbase, nbuck);
    k_finefill2<<<nbuck, 1024, 0, stream>>>(stageg, bcnt, bbase, offs, dinv, col, N, nbuck);

    int gbE = (N + 63) / 64;
    int aggthreads = ((N + 7) / 8) * 64;
    int aggblocks = (aggthreads + 255) / 256;

    // encoder + layer-0 GEMM fused: h = x@Wenc+b ; hwbA = (dinv*h)@Wg0
    k_enc_fused<<<gbE, 256, 0, stream>>>(
        x, (const uint4*)wfragg, b_enc, (const uint4*)(wfragg + (size_t)1 * 4096),
        dinv, h, hwbA, N);
    // layers 0..2: agg + wave-local next-layer GEMM (ping-pong)
    k_agg_fused<<<aggblocks, 256, 0, stream>>>(hwbA, offs, col, dinv, bg + 0 * 64, h,
                                               (const uint4*)(wfragg + (size_t)2 * 4096), hwbB, N);
    k_agg_fused<<<aggblocks, 256, 0, stream>>>(hwbB, offs, col, dinv, bg + 1 * 64, h,
                                               (const uint4*)(wfragg + (size_t)3 * 4096), hwbA, N);
    k_agg_fused<<<aggblocks, 256, 0, stream>>>(hwbA, offs, col, dinv, bg + 2 * 64, h,
                                               (const uint4*)(wfragg + (size_t)4 * 4096), hwbB, N);
    // layer 3: agg + fused MLP readout v2 (no h write)
    k_agg_out<<<aggblocks, 256, 0, stream>>>(hwbB, offs, col, dinv, bg + 3 * 64, h,
                                             W0, b0, W1, b1, W2, b2, (float*)d_out, N);
}

// Round 20
// 216.134 us; speedup vs baseline: 1.3735x; 1.0712x over previous
//
#include <hip/hip_runtime.h>

typedef __attribute__((ext_vector_type(8))) short bf16x8_t;
typedef __attribute__((ext_vector_type(4))) float f32x4_t;

#define PINF(x) asm volatile("" : "+v"(x))

// ---------------- partition: edges -> coarse buckets (256 nodes each) ----------------

#define PCHUNK 4096
#define PTHREADS 512
#define EPT (PCHUNK / PTHREADS)
#define NBUCK_MAX 400
#define BCAP 6144

__global__ __launch_bounds__(PTHREADS)
void k_partition2(const int* __restrict__ src, const int* __restrict__ dst,
                  int* __restrict__ bcnt, unsigned int* __restrict__ stageg,
                  int E, int nbuck) {
    __shared__ int hist[NBUCK_MAX];
    __shared__ int boffs[NBUCK_MAX];
    __shared__ int cur[NBUCK_MAX];
    __shared__ int gbase[NBUCK_MAX];
    __shared__ int tmp[PTHREADS];
    __shared__ unsigned int stage[PCHUNK];
    __shared__ unsigned short sbid[PCHUNK];

    int tid = threadIdx.x;
    int ebase = blockIdx.x * PCHUNK;
    int ecount = min(PCHUNK, E - ebase);

    if (tid < NBUCK_MAX) hist[tid] = 0;
    __syncthreads();

    int dreg[EPT], sreg[EPT];
#pragma unroll
    for (int k = 0; k < EPT; k++) {
        int e = ebase + tid + k * PTHREADS;
        if (tid + k * PTHREADS < ecount) {
            dreg[k] = dst[e];
            sreg[k] = src[e];
            atomicAdd(&hist[dreg[k] >> 8], 1);
        } else dreg[k] = -1;
    }
    __syncthreads();

    int v = (tid < nbuck) ? hist[tid] : 0;
    tmp[tid] = v;
    __syncthreads();
    for (int d = 1; d < PTHREADS; d <<= 1) {
        int t = (tid >= d) ? tmp[tid - d] : 0;
        __syncthreads();
        tmp[tid] += t;
        __syncthreads();
    }
    if (tid < nbuck) { boffs[tid] = tmp[tid] - v; cur[tid] = tmp[tid] - v; }
    __syncthreads();

#pragma unroll
    for (int k = 0; k < EPT; k++) {
        if (dreg[k] >= 0) {
            int b = dreg[k] >> 8;
            int p = atomicAdd(&cur[b], 1);
            stage[p] = ((unsigned int)(dreg[k] & 255) << 17) | (unsigned int)sreg[k];
            sbid[p] = (unsigned short)b;
        }
    }
    __syncthreads();

    if (tid < nbuck) {
        int c = cur[tid] - boffs[tid];
        if (c > 0) gbase[tid] = atomicAdd(&bcnt[tid], c);
    }
    __syncthreads();

    for (int i = tid; i < ecount; i += PTHREADS) {
        int b = sbid[i];
        stageg[(size_t)b * BCAP + gbase[b] + (i - boffs[b])] = stage[i];
    }
}

// ---------------- bucket scan ----------------

__global__ __launch_bounds__(512)
void k_bucket_scan(const int* __restrict__ bcnt, int* __restrict__ bbase, int nbuck) {
    __shared__ int tmp[512];
    int tid = threadIdx.x;
    int v = (tid < nbuck) ? bcnt[tid] : 0;
    tmp[tid] = v;
    __syncthreads();
    for (int d = 1; d < 512; d <<= 1) {
        int t = (tid >= d) ? tmp[tid - d] : 0;
        __syncthreads();
        tmp[tid] += t;
        __syncthreads();
    }
    if (tid < nbuck) bbase[tid] = tmp[tid] - v;
    if (tid == nbuck - 1) bbase[nbuck] = tmp[tid];
}

// ---------------- fine fill: bucket-staged -> dense CSR (offs, dinv, col) ----------------

__global__ __launch_bounds__(1024)
void k_finefill2(const unsigned int* __restrict__ stageg, const int* __restrict__ bcnt,
                 const int* __restrict__ bbase, int* __restrict__ offs,
                 float* __restrict__ dinv, int* __restrict__ col, int N, int nbuck) {
    __shared__ int cnt0[256];
    __shared__ int excl[256];
    __shared__ int cur[256];
    __shared__ unsigned int stage[BCAP];
    int b = blockIdx.x;
    int tid = threadIdx.x;
    int nbase = b << 8;
    int nn = min(256, N - nbase);
    int n = bcnt[b];
    int base = bbase[b];
    const unsigned int* sg = stageg + (size_t)b * BCAP;

    if (tid < 256) cnt0[tid] = 0;
    __syncthreads();

    for (int i = tid; i < n; i += 1024)
        atomicAdd(&cnt0[sg[i] >> 17], 1);
    __syncthreads();

    if (tid < 256) excl[tid] = cnt0[tid];
    __syncthreads();
    for (int d = 1; d < 256; d <<= 1) {
        int t = 0;
        if (tid < 256 && tid >= d) t = excl[tid - d];
        __syncthreads();
        if (tid < 256) excl[tid] += t;
        __syncthreads();
    }
    if (tid < 256) {
        int e = excl[tid] - cnt0[tid];
        cur[tid] = e;
        if (tid < nn) {
            offs[nbase + tid] = base + e;
            dinv[nbase + tid] = rsqrtf((float)(cnt0[tid] + 1));  // +1 self-loop
        }
    }
    if (b == nbuck - 1 && tid == 0) offs[N] = bbase[nbuck];
    __syncthreads();

    for (int i = tid; i < n; i += 1024) {
        unsigned int v = sg[i];
        int p = atomicAdd(&cur[v >> 17], 1);
        stage[p] = v & 0x1FFFFu;
    }
    __syncthreads();
    for (int i = tid; i < n; i += 1024)
        col[base + i] = (int)stage[i];
}

// ---------------- bf16 helpers ----------------

__device__ __forceinline__ unsigned int bf16rne(float x) {
    unsigned int u = __float_as_uint(x);
    return (u + 0x7FFFu + ((u >> 16) & 1u)) >> 16;
}
__device__ __forceinline__ float u2flo(unsigned int u) { return __uint_as_float(u << 16); }
__device__ __forceinline__ float u2fhi(unsigned int u) { return __uint_as_float(u & 0xFFFF0000u); }

__device__ __forceinline__ void split2(float a, float b, unsigned int& hi, unsigned int& lo) {
    unsigned int ha = bf16rne(a), hb = bf16rne(b);
    float ra = a - u2flo(ha), rb = b - u2flo(hb);
    hi = ha | (hb << 16);
    lo = bf16rne(ra) | (bf16rne(rb) << 16);
}

union FragU { uint4 u4; bf16x8_t bf; };

// ---------------- W fragment precompute (once); block 0 also zeros bcnt ----------------

__global__ __launch_bounds__(256)
void k_wsplit(const float* __restrict__ Wenc, const float* __restrict__ Wg,
              unsigned int* __restrict__ wfragg, int* __restrict__ bcnt) {
    int m = blockIdx.x;                 // 0=enc, 1..4 = Wg layer m-1
    int tid = threadIdx.x;
    if (m == 0 && tid < 256) { bcnt[tid] = 0; bcnt[tid + 256] = 0; }
    const float* W = (m == 0) ? Wenc : (Wg + (size_t)(m - 1) * 4096);
    unsigned int* wb = wfragg + (size_t)m * 4096;
#pragma unroll
    for (int i = 0; i < 16; i++) {
        int flat = tid * 16 + i;
        int mm = flat & 3;
        int l = (flat >> 2) & 63;
        int fp = flat >> 8;
        int p = fp & 1;
        int f = fp >> 1;
        int ct = f >> 1, kh = f & 1;
        int k = kh * 32 + ((l >> 4) << 3) + 2 * mm;
        int c = ct * 16 + (l & 15);
        float w0 = W[k * 64 + c];
        float w1 = W[(k + 1) * 64 + c];
        unsigned int hi, lo;
        split2(w0, w1, hi, lo);
        wb[flat] = p ? lo : hi;
    }
}

// ---------------- Encoder fused: h = x@Wenc + b ; hwb0 = (dinv*h)@Wg0 ----------------

__global__ __launch_bounds__(256)
void k_enc_fused(const float* __restrict__ x, const uint4* __restrict__ wfE,
                 const float* __restrict__ benc, const uint4* __restrict__ wfG,
                 const float* __restrict__ dinv, float* __restrict__ h,
                 unsigned short* __restrict__ hwb_out, int N) {
    __shared__ float hlds[64 * 68];

    int tid = threadIdx.x;
    int lane = tid & 63;
    int w = tid >> 6;
    int rowbase = blockIdx.x * 64 + w * 16;

    FragU ahi[2], alo[2];
    {
        int row = rowbase + (lane & 15);
        int rc = min(row, N - 1);
#pragma unroll
        for (int kh = 0; kh < 2; kh++) {
            const float4* hp = (const float4*)(x + (size_t)rc * 64 + kh * 32 + ((lane >> 4) << 3));
            float4 p0 = hp[0], p1 = hp[1];
            split2(p0.x, p0.y, ahi[kh].u4.x, alo[kh].u4.x);
            split2(p0.z, p0.w, ahi[kh].u4.y, alo[kh].u4.y);
            split2(p1.x, p1.y, ahi[kh].u4.z, alo[kh].u4.z);
            split2(p1.z, p1.w, ahi[kh].u4.w, alo[kh].u4.w);
        }
    }

    f32x4_t acc[4];
#pragma unroll
    for (int ct = 0; ct < 4; ct++) {
        float b = benc[ct * 16 + (lane & 15)];
        acc[ct] = (f32x4_t){b, b, b, b};
    }
#pragma unroll
    for (int ct = 0; ct < 4; ct++) {
#pragma unroll
        for (int kh = 0; kh < 2; kh++) {
            FragU bhi, blo;
            bhi.u4 = wfE[((ct * 2 + kh) * 2 + 0) * 64 + lane];
            blo.u4 = wfE[((ct * 2 + kh) * 2 + 1) * 64 + lane];
            acc[ct] = __builtin_amdgcn_mfma_f32_16x16x32_bf16(ahi[kh].bf, bhi.bf, acc[ct], 0, 0, 0);
            acc[ct] = __builtin_amdgcn_mfma_f32_16x16x32_bf16(alo[kh].bf, bhi.bf, acc[ct], 0, 0, 0);
            acc[ct] = __builtin_amdgcn_mfma_f32_16x16x32_bf16(ahi[kh].bf, blo.bf, acc[ct], 0, 0, 0);
        }
    }

    float dv[4];
#pragma unroll
    for (int r = 0; r < 4; r++) {
        int row = rowbase + ((lane >> 4) << 2) + r;
        dv[r] = dinv[min(row, N - 1)];
    }
#pragma unroll
    for (int ct = 0; ct < 4; ct++) {
#pragma unroll
        for (int r = 0; r < 4; r++) {
            int row = rowbase + ((lane >> 4) << 2) + r;
            float v = acc[ct][r];
            if (row < N) h[(size_t)row * 64 + ct * 16 + (lane & 15)] = v;
            hlds[(w * 16 + ((lane >> 4) << 2) + r) * 68 + ct * 16 + (lane & 15)] = v * dv[r];
        }
    }
    __syncthreads();

    FragU a2hi[2], a2lo[2];
#pragma unroll
    for (int kh = 0; kh < 2; kh++) {
        const float4* hp = (const float4*)(hlds + (w * 16 + (lane & 15)) * 68 + kh * 32 + ((lane >> 4) << 3));
        float4 p0 = hp[0], p1 = hp[1];
        split2(p0.x, p0.y, a2hi[kh].u4.x, a2lo[kh].u4.x);
        split2(p0.z, p0.w, a2hi[kh].u4.y, a2lo[kh].u4.y);
        split2(p1.x, p1.y, a2hi[kh].u4.z, a2lo[kh].u4.z);
        split2(p1.z, p1.w, a2hi[kh].u4.w, a2lo[kh].u4.w);
    }

#pragma unroll
    for (int ct = 0; ct < 4; ct++) {
        f32x4_t a2 = (f32x4_t){0.f, 0.f, 0.f, 0.f};
#pragma unroll
        for (int kh = 0; kh < 2; kh++) {
            FragU bhi, blo;
            bhi.u4 = wfG[((ct * 2 + kh) * 2 + 0) * 64 + lane];
            blo.u4 = wfG[((ct * 2 + kh) * 2 + 1) * 64 + lane];
            a2 = __builtin_amdgcn_mfma_f32_16x16x32_bf16(a2hi[kh].bf, bhi.bf, a2, 0, 0, 0);
            a2 = __builtin_amdgcn_mfma_f32_16x16x32_bf16(a2lo[kh].bf, bhi.bf, a2, 0, 0, 0);
            a2 = __builtin_amdgcn_mfma_f32_16x16x32_bf16(a2hi[kh].bf, blo.bf, a2, 0, 0, 0);
        }
#pragma unroll
        for (int r = 0; r < 4; r++) {
            float v = a2[r];
            float vo = __shfl_xor(v, 1);
            int row = rowbase + ((lane >> 4) << 2) + r;
            if (!(lane & 1) && row < N) {
                unsigned int pk = bf16rne(v) | (bf16rne(vo) << 16);
                *(unsigned int*)(hwb_out + (size_t)row * 64 + ct * 16 + (lane & 15)) = pk;
            }
        }
    }
}

// ---------------- Fused agg + wave-local next-layer GEMM (layers 0..2) ----------------

__global__ __launch_bounds__(256, 4)
void k_agg_fused(const unsigned short* __restrict__ hwb_in, const int* __restrict__ offs,
                 const int* __restrict__ col, const float* __restrict__ dinv,
                 const float* __restrict__ bg, float* __restrict__ h,
                 const uint4* __restrict__ wnext, unsigned short* __restrict__ hwb_out,
                 int N) {
    __shared__ uint4 wlds[16 * 64];

    int tid = threadIdx.x;
#pragma unroll
    for (int i = 0; i < 4; i++)
        wlds[tid + i * 256] = wnext[tid + i * 256];
    __syncthreads();   // before gather: no coupling of gather chains

    int t = blockIdx.x * 256 + tid;
    int wid = t >> 6;
    int lane = tid & 63;
    int G = lane >> 3;
    int L = lane & 7;
    int node = wid * 8 + G;
    bool valid = node < N;
    int nc = valid ? node : N - 1;

    int start = offs[nc];
    int end = valid ? offs[nc + 1] : start;

    float dn = dinv[nc];
    float* hrow = h + (size_t)nc * 64 + L * 8;
    float4 hr0 = ((const float4*)hrow)[0];
    float4 hr1 = ((const float4*)hrow)[1];
    const float* bgp = bg + L * 8;
    float bs0 = bgp[0] + hr0.x, bs1 = bgp[1] + hr0.y, bs2 = bgp[2] + hr0.z, bs3 = bgp[3] + hr0.w;
    float bs4 = bgp[4] + hr1.x, bs5 = bgp[5] + hr1.y, bs6 = bgp[6] + hr1.z, bs7 = bgp[7] + hr1.w;
    PINF(bs0); PINF(bs1); PINF(bs2); PINF(bs3);
    PINF(bs4); PINF(bs5); PINF(bs6); PINF(bs7); PINF(dn);

    uint4 v = ((const uint4*)(hwb_in + (size_t)nc * 64))[L];
    float a0 = u2flo(v.x), a1 = u2fhi(v.x);
    float a2 = u2flo(v.y), a3 = u2fhi(v.y);
    float a4 = u2flo(v.z), a5 = u2fhi(v.z);
    float a6 = u2flo(v.w), a7 = u2fhi(v.w);

    int last = (end > start) ? (end - 1) : 0;
    int e = start;
    int cc0 = col[min(e + 0, last)];
    int cc1 = col[min(e + 1, last)];
    int cc2 = col[min(e + 2, last)];
    int cc3 = col[min(e + 3, last)];
    for (;;) {
        bool act0 = e < end;
        if (__ballot(act0) == 0ULL) break;
        bool act1 = e + 1 < end, act2 = e + 2 < end, act3 = e + 3 < end;
        uint4 v0 = ((const uint4*)(hwb_in + (size_t)cc0 * 64))[L];
        uint4 v1 = ((const uint4*)(hwb_in + (size_t)cc1 * 64))[L];
        uint4 v2 = ((const uint4*)(hwb_in + (size_t)cc2 * 64))[L];
        uint4 v3 = ((const uint4*)(hwb_in + (size_t)cc3 * 64))[L];
        int en = e + 4;
        cc0 = col[min(en + 0, last)];
        cc1 = col[min(en + 1, last)];
        cc2 = col[min(en + 2, last)];
        cc3 = col[min(en + 3, last)];
        if (!act0) { v0.x = 0u; v0.y = 0u; v0.z = 0u; v0.w = 0u; }
        if (!act1) { v1.x = 0u; v1.y = 0u; v1.z = 0u; v1.w = 0u; }
        if (!act2) { v2.x = 0u; v2.y = 0u; v2.z = 0u; v2.w = 0u; }
        if (!act3) { v3.x = 0u; v3.y = 0u; v3.z = 0u; v3.w = 0u; }
        a0 += (u2flo(v0.x) + u2flo(v1.x)) + (u2flo(v2.x) + u2flo(v3.x));
        a1 += (u2fhi(v0.x) + u2fhi(v1.x)) + (u2fhi(v2.x) + u2fhi(v3.x));
        a2 += (u2flo(v0.y) + u2flo(v1.y)) + (u2flo(v2.y) + u2flo(v3.y));
        a3 += (u2fhi(v0.y) + u2fhi(v1.y)) + (u2fhi(v2.y) + u2fhi(v3.y));
        a4 += (u2flo(v0.z) + u2flo(v1.z)) + (u2flo(v2.z) + u2flo(v3.z));
        a5 += (u2fhi(v0.z) + u2fhi(v1.z)) + (u2fhi(v2.z) + u2fhi(v3.z));
        a6 += (u2flo(v0.w) + u2flo(v1.w)) + (u2flo(v2.w) + u2flo(v3.w));
        a7 += (u2fhi(v0.w) + u2fhi(v1.w)) + (u2fhi(v2.w) + u2fhi(v3.w));
        e = en;
    }

    // epilogue (relu on)
    float4 o0, o1;
    o0.x = fmaxf(fmaf(dn, a0, bs0), 0.f);
    o0.y = fmaxf(fmaf(dn, a1, bs1), 0.f);
    o0.z = fmaxf(fmaf(dn, a2, bs2), 0.f);
    o0.w = fmaxf(fmaf(dn, a3, bs3), 0.f);
    o1.x = fmaxf(fmaf(dn, a4, bs4), 0.f);
    o1.y = fmaxf(fmaf(dn, a5, bs5), 0.f);
    o1.z = fmaxf(fmaf(dn, a6, bs6), 0.f);
    o1.w = fmaxf(fmaf(dn, a7, bs7), 0.f);
    if (valid) {
        ((float4*)hrow)[0] = o0;
        ((float4*)hrow)[1] = o1;
    }

    // ---- wave-local fused GEMM: hwb_out[node] = (dinv*h)@Wnext ----
    float sv0 = o0.x * dn, sv1 = o0.y * dn, sv2 = o0.z * dn, sv3 = o0.w * dn;
    float sv4 = o1.x * dn, sv5 = o1.y * dn, sv6 = o1.z * dn, sv7 = o1.w * dn;

    int r = lane & 15;
    int kb = lane >> 4;
    int srcA = (r & 7) * 8 + kb;       // kh=0 source lane
    int srcB = (r & 7) * 8 + 4 + kb;   // kh=1 source lane

    FragU ahi0, alo0, ahi1, alo1;
    {
        float c0 = __shfl(sv0, srcA), c1 = __shfl(sv1, srcA);
        float c2 = __shfl(sv2, srcA), c3 = __shfl(sv3, srcA);
        float c4 = __shfl(sv4, srcA), c5 = __shfl(sv5, srcA);
        float c6 = __shfl(sv6, srcA), c7 = __shfl(sv7, srcA);
        split2(c0, c1, ahi0.u4.x, alo0.u4.x);
        split2(c2, c3, ahi0.u4.y, alo0.u4.y);
        split2(c4, c5, ahi0.u4.z, alo0.u4.z);
        split2(c6, c7, ahi0.u4.w, alo0.u4.w);
    }
    {
        float c0 = __shfl(sv0, srcB), c1 = __shfl(sv1, srcB);
        float c2 = __shfl(sv2, srcB), c3 = __shfl(sv3, srcB);
        float c4 = __shfl(sv4, srcB), c5 = __shfl(sv5, srcB);
        float c6 = __shfl(sv6, srcB), c7 = __shfl(sv7, srcB);
        split2(c0, c1, ahi1.u4.x, alo1.u4.x);
        split2(c2, c3, ahi1.u4.y, alo1.u4.y);
        split2(c4, c5, ahi1.u4.z, alo1.u4.z);
        split2(c6, c7, ahi1.u4.w, alo1.u4.w);
    }

    f32x4_t acc[4];
#pragma unroll
    for (int ct = 0; ct < 4; ct++) acc[ct] = (f32x4_t){0.f, 0.f, 0.f, 0.f};

#pragma unroll
    for (int ct = 0; ct < 4; ct++) {
        FragU bh0, bl0, bh1, bl1;
        bh0.u4 = wlds[((ct * 2 + 0) * 2 + 0) * 64 + lane];
        bl0.u4 = wlds[((ct * 2 + 0) * 2 + 1) * 64 + lane];
        bh1.u4 = wlds[((ct * 2 + 1) * 2 + 0) * 64 + lane];
        bl1.u4 = wlds[((ct * 2 + 1) * 2 + 1) * 64 + lane];
        acc[ct] = __builtin_amdgcn_mfma_f32_16x16x32_bf16(ahi0.bf, bh0.bf, acc[ct], 0, 0, 0);
        acc[ct] = __builtin_amdgcn_mfma_f32_16x16x32_bf16(alo0.bf, bh0.bf, acc[ct], 0, 0, 0);
        acc[ct] = __builtin_amdgcn_mfma_f32_16x16x32_bf16(ahi0.bf, bl0.bf, acc[ct], 0, 0, 0);
        acc[ct] = __builtin_amdgcn_mfma_f32_16x16x32_bf16(ahi1.bf, bh1.bf, acc[ct], 0, 0, 0);
        acc[ct] = __builtin_amdgcn_mfma_f32_16x16x32_bf16(alo1.bf, bh1.bf, acc[ct], 0, 0, 0);
        acc[ct] = __builtin_amdgcn_mfma_f32_16x16x32_bf16(ahi1.bf, bl1.bf, acc[ct], 0, 0, 0);
    }

    int wbase = wid * 8;
#pragma unroll
    for (int ct = 0; ct < 4; ct++) {
#pragma unroll
        for (int rr = 0; rr < 4; rr++) {
            float vv = acc[ct][rr];
            float vo = __shfl_xor(vv, 1);
            int orow = ((lane >> 4) << 2) + rr;
            int onode = wbase + orow;
            if (!(lane & 1) && orow < 8 && onode < N) {
                unsigned int pk = bf16rne(vv) | (bf16rne(vo) << 16);
                *(unsigned int*)(hwb_out + (size_t)onode * 64 + ct * 16 + (lane & 15)) = pk;
            }
        }
    }
}

// ---------------- Final agg + fused MLP readout v3 (layer 3) ----------------
// v2 post-mortem: lane-dependent W0/W1 addressing -> ~300 per-lane VMEM loads
// per thread (62us vs 46 split). v3: stage W0/W1/W2/b0/b1 into LDS at block
// start (10.4KB coalesced copy, barrier BEFORE gather); tail reads become
// conflict-free ds_read_b128/b64 broadcasts. Math identical to v2.

__global__ __launch_bounds__(256)
void k_agg_out(const unsigned short* __restrict__ hwb, const int* __restrict__ offs,
               const int* __restrict__ col, const float* __restrict__ dinv,
               const float* __restrict__ bg, const float* __restrict__ h,
               const float* __restrict__ W0, const float* __restrict__ b0,
               const float* __restrict__ W1, const float* __restrict__ b1,
               const float* __restrict__ W2, const float* __restrict__ b2,
               float* __restrict__ out, int N) {
    __shared__ float w0l[2048];
    __shared__ float w1l[512];
    __shared__ float w2l[16];
    __shared__ float b0l[32];
    __shared__ float b1l[16];

    int tid = threadIdx.x;
    {
        float4* d4 = (float4*)w0l;
        const float4* s4 = (const float4*)W0;
        d4[tid] = s4[tid];
        d4[tid + 256] = s4[tid + 256];
        if (tid < 128) ((float4*)w1l)[tid] = ((const float4*)W1)[tid];
        if (tid < 16) w2l[tid] = W2[tid];
        if (tid < 32) b0l[tid] = b0[tid];
        if (tid < 16) b1l[tid] = b1[tid];
    }
    __syncthreads();   // before gather

    int t = blockIdx.x * blockDim.x + tid;
    int wid = t >> 6;
    int lane = tid & 63;
    int G = lane >> 3;
    int L = lane & 7;
    int gb = lane & 56;                 // group base lane
    int node = wid * 8 + G;
    bool valid = node < N;
    int nc = valid ? node : N - 1;

    int start = offs[nc];
    int end = valid ? offs[nc + 1] : start;

    float dn = dinv[nc];
    const float* hrow = h + (size_t)nc * 64 + L * 8;
    float4 hr0 = ((const float4*)hrow)[0];
    float4 hr1 = ((const float4*)hrow)[1];
    const float* bgp = bg + L * 8;
    float bs0 = bgp[0] + hr0.x, bs1 = bgp[1] + hr0.y, bs2 = bgp[2] + hr0.z, bs3 = bgp[3] + hr0.w;
    float bs4 = bgp[4] + hr1.x, bs5 = bgp[5] + hr1.y, bs6 = bgp[6] + hr1.z, bs7 = bgp[7] + hr1.w;
    PINF(bs0); PINF(bs1); PINF(bs2); PINF(bs3);
    PINF(bs4); PINF(bs5); PINF(bs6); PINF(bs7); PINF(dn);

    uint4 v = ((const uint4*)(hwb + (size_t)nc * 64))[L];
    float a0 = u2flo(v.x), a1 = u2fhi(v.x);
    float a2 = u2flo(v.y), a3 = u2fhi(v.y);
    float a4 = u2flo(v.z), a5 = u2fhi(v.z);
    float a6 = u2flo(v.w), a7 = u2fhi(v.w);

    int last = (end > start) ? (end - 1) : 0;
    int e = start;
    int cc0 = col[min(e + 0, last)];
    int cc1 = col[min(e + 1, last)];
    int cc2 = col[min(e + 2, last)];
    int cc3 = col[min(e + 3, last)];
    for (;;) {
        bool act0 = e < end;
        if (__ballot(act0) == 0ULL) break;
        bool act1 = e + 1 < end, act2 = e + 2 < end, act3 = e + 3 < end;
        uint4 v0 = ((const uint4*)(hwb + (size_t)cc0 * 64))[L];
        uint4 v1 = ((const uint4*)(hwb + (size_t)cc1 * 64))[L];
        uint4 v2 = ((const uint4*)(hwb + (size_t)cc2 * 64))[L];
        uint4 v3 = ((const uint4*)(hwb + (size_t)cc3 * 64))[L];
        int en = e + 4;
        cc0 = col[min(en + 0, last)];
        cc1 = col[min(en + 1, last)];
        cc2 = col[min(en + 2, last)];
        cc3 = col[min(en + 3, last)];
        if (!act0) { v0.x = 0u; v0.y = 0u; v0.z = 0u; v0.w = 0u; }
        if (!act1) { v1.x = 0u; v1.y = 0u; v1.z = 0u; v1.w = 0u; }
        if (!act2) { v2.x = 0u; v2.y = 0u; v2.z = 0u; v2.w = 0u; }
        if (!act3) { v3.x = 0u; v3.y = 0u; v3.z = 0u; v3.w = 0u; }
        a0 += (u2flo(v0.x) + u2flo(v1.x)) + (u2flo(v2.x) + u2flo(v3.x));
        a1 += (u2fhi(v0.x) + u2fhi(v1.x)) + (u2fhi(v2.x) + u2fhi(v3.x));
        a2 += (u2flo(v0.y) + u2flo(v1.y)) + (u2flo(v2.y) + u2flo(v3.y));
        a3 += (u2fhi(v0.y) + u2fhi(v1.y)) + (u2fhi(v2.y) + u2fhi(v3.y));
        a4 += (u2flo(v0.z) + u2flo(v1.z)) + (u2flo(v2.z) + u2flo(v3.z));
        a5 += (u2fhi(v0.z) + u2fhi(v1.z)) + (u2fhi(v2.z) + u2fhi(v3.z));
        a6 += (u2flo(v0.w) + u2flo(v1.w)) + (u2flo(v2.w) + u2flo(v3.w));
        a7 += (u2fhi(v0.w) + u2fhi(v1.w)) + (u2fhi(v2.w) + u2fhi(v3.w));
        e = en;
    }

    // layer-3 h (no relu), registers only: lane L holds channels L*8..L*8+7
    float hk0 = fmaf(dn, a0, bs0);
    float hk1 = fmaf(dn, a1, bs1);
    float hk2 = fmaf(dn, a2, bs2);
    float hk3 = fmaf(dn, a3, bs3);
    float hk4 = fmaf(dn, a4, bs4);
    float hk5 = fmaf(dn, a5, bs5);
    float hk6 = fmaf(dn, a6, bs6);
    float hk7 = fmaf(dn, a7, bs7);

    // ---- stage 1 (64->32): lane owns cols L*4..L*4+3, W0 via ds_read_b128 ----
    float4 bb0 = ((const float4*)b0l)[L];
    float t0a = bb0.x, t0b = bb0.y, t0c = bb0.z, t0d = bb0.w;
#pragma unroll
    for (int s = 0; s < 8; s++) {
        float y0 = __shfl(hk0, gb + s), y1 = __shfl(hk1, gb + s);
        float y2 = __shfl(hk2, gb + s), y3 = __shfl(hk3, gb + s);
        float y4 = __shfl(hk4, gb + s), y5 = __shfl(hk5, gb + s);
        float y6 = __shfl(hk6, gb + s), y7 = __shfl(hk7, gb + s);
#pragma unroll
        for (int j = 0; j < 8; j++) {
            float yj = (j == 0) ? y0 : (j == 1) ? y1 : (j == 2) ? y2 : (j == 3) ? y3
                     : (j == 4) ? y4 : (j == 5) ? y5 : (j == 6) ? y6 : y7;
            float4 wv = ((const float4*)w0l)[(s * 8 + j) * 8 + L];
            t0a = fmaf(yj, wv.x, t0a);
            t0b = fmaf(yj, wv.y, t0b);
            t0c = fmaf(yj, wv.z, t0c);
            t0d = fmaf(yj, wv.w, t0d);
        }
    }
    t0a = fmaxf(t0a, 0.f); t0b = fmaxf(t0b, 0.f);
    t0c = fmaxf(t0c, 0.f); t0d = fmaxf(t0d, 0.f);

    // ---- stage 2 (32->16): lane owns cols L*2, L*2+1, W1 via ds_read_b64 ----
    float2 bb1 = ((const float2*)b1l)[L];
    float t1a = bb1.x, t1b = bb1.y;
#pragma unroll
    for (int s = 0; s < 8; s++) {
        float z0 = __shfl(t0a, gb + s), z1 = __shfl(t0b, gb + s);
        float z2 = __shfl(t0c, gb + s), z3 = __shfl(t0d, gb + s);
        float2 w0v = ((const float2*)w1l)[((s * 4 + 0) * 16 >> 1) + L];
        float2 w1v = ((const float2*)w1l)[((s * 4 + 1) * 16 >> 1) + L];
        float2 w2v = ((const float2*)w1l)[((s * 4 + 2) * 16 >> 1) + L];
        float2 w3v = ((const float2*)w1l)[((s * 4 + 3) * 16 >> 1) + L];
        t1a = fmaf(z0, w0v.x, t1a);  t1b = fmaf(z0, w0v.y, t1b);
        t1a = fmaf(z1, w1v.x, t1a);  t1b = fmaf(z1, w1v.y, t1b);
        t1a = fmaf(z2, w2v.x, t1a);  t1b = fmaf(z2, w2v.y, t1b);
        t1a = fmaf(z3, w3v.x, t1a);  t1b = fmaf(z3, w3v.y, t1b);
    }
    t1a = fmaxf(t1a, 0.f);
    t1b = fmaxf(t1b, 0.f);

    // ---- stage 3 (16->1) ----
    float2 w2v = ((const float2*)w2l)[L];
    float y = t1a * w2v.x + t1b * w2v.y;
    y += __shfl_xor(y, 1);
    y += __shfl_xor(y, 2);
    y += __shfl_xor(y, 4);

    if (valid && L == 0) out[node] = y + b2[0];
}

// ---------------- launch ----------------

extern "C" void kernel_launch(void* const* d_in, const int* in_sizes, int n_in,
                              void* d_out, int out_size, void* d_ws, size_t ws_size,
                              hipStream_t stream) {
    const float* x     = (const float*)d_in[0];
    const int*   eidx  = (const int*)d_in[1];
    const float* W_enc = (const float*)d_in[2];
    const float* b_enc = (const float*)d_in[3];
    const float* Wg    = (const float*)d_in[4];
    const float* bg    = (const float*)d_in[5];
    const float* W0    = (const float*)d_in[6];
    const float* b0    = (const float*)d_in[7];
    const float* W1    = (const float*)d_in[8];
    const float* b1    = (const float*)d_in[9];
    const float* W2    = (const float*)d_in[10];
    const float* b2    = (const float*)d_in[11];

    int N = in_sizes[0] / 64;
    int E = in_sizes[1] / 2;
    const int* esrc = eidx;
    const int* edst = eidx + E;
    int nbuck = (N + 255) >> 8;

    char* w = (char*)d_ws;
    auto alloc = [&](size_t bytes) -> char* {
        char* p = w;
        w += (bytes + 255) & ~(size_t)255;
        return p;
    };
    int*   bcnt  = (int*)alloc(512 * 4);
    int*   bbase = (int*)alloc(512 * 4);
    int*   offs  = (int*)alloc((size_t)(N + 1) * 4);
    int*   col   = (int*)alloc((size_t)E * 4);
    unsigned int* stageg = (unsigned int*)alloc((size_t)nbuck * BCAP * 4);
    float* dinv  = (float*)alloc((size_t)N * 4);
    float* h     = (float*)alloc((size_t)N * 64 * 4);
    unsigned short* hwbA = (unsigned short*)alloc((size_t)N * 64 * 2);
    unsigned short* hwbB = (unsigned short*)alloc((size_t)N * 64 * 2);
    unsigned int* wfragg = (unsigned int*)alloc(5 * 4096 * 4);  // 80KB frag images

    k_wsplit<<<5, 256, 0, stream>>>(W_enc, Wg, wfragg, bcnt);
    k_partition2<<<(E + PCHUNK - 1) / PCHUNK, PTHREADS, 0, stream>>>(esrc, edst, bcnt, stageg, E, nbuck);
    k_bucket_scan<<<1, 512, 0, stream>>>(bcnt, bbase, nbuck);
    k_finefill2<<<nbuck, 1024, 0, stream>>>(stageg, bcnt, bbase, offs, dinv, col, N, nbuck);

    int gbE = (N + 63) / 64;
    int aggthreads = ((N + 7) / 8) * 64;
    int aggblocks = (aggthreads + 255) / 256;

    // encoder + layer-0 GEMM fused: h = x@Wenc+b ; hwbA = (dinv*h)@Wg0
    k_enc_fused<<<gbE, 256, 0, stream>>>(
        x, (const uint4*)wfragg, b_enc, (const uint4*)(wfragg + (size_t)1 * 4096),
        dinv, h, hwbA, N);
    // layers 0..2: agg + wave-local next-layer GEMM (ping-pong)
    k_agg_fused<<<aggblocks, 256, 0, stream>>>(hwbA, offs, col, dinv, bg + 0 * 64, h,
                                               (const uint4*)(wfragg + (size_t)2 * 4096), hwbB, N);
    k_agg_fused<<<aggblocks, 256, 0, stream>>>(hwbB, offs, col, dinv, bg + 1 * 64, h,
                                               (const uint4*)(wfragg + (size_t)3 * 4096), hwbA, N);
    k_agg_fused<<<aggblocks, 256, 0, stream>>>(hwbA, offs, col, dinv, bg + 2 * 64, h,
                                               (const uint4*)(wfragg + (size_t)4 * 4096), hwbB, N);
    // layer 3: agg + fused MLP readout v3 (LDS weights, no h write)
    k_agg_out<<<aggblocks, 256, 0, stream>>>(hwbB, offs, col, dinv, bg + 3 * 64, h,
                                             W0, b0, W1, b1, W2, b2, (float*)d_out, N);
}